// Round 1
// baseline (458.456 us; speedup 1.0000x reference)
//
#include <hip/hip_runtime.h>
#include <hip/hip_bf16.h>
#include <math.h>

#define NN 4
#define CC 15
#define HH 320
#define WW 320
#define HW (HH*WW)          // 102400
#define FF 32
#define KS 11
#define PADN 11
#define CPAD 5
#define HP 342
#define NK 31
#define NCB (NN*CC)
#define TABN 256            // intervals; 257 entries, stride 260

typedef short bf16x8 __attribute__((ext_vector_type(8)));
typedef float f32x4 __attribute__((ext_vector_type(4)));
typedef unsigned short u16x4 __attribute__((ext_vector_type(4)));

#define MFMA16 __builtin_amdgcn_mfma_f32_16x16x32_bf16

__device__ __forceinline__ unsigned int pack_bf(float r, float i) {
  __hip_bfloat16 hr = __float2bfloat16(r), hi = __float2bfloat16(i);
  unsigned short ur = *(unsigned short*)&hr, ui = *(unsigned short*)&hi;
  return (unsigned int)ur | ((unsigned int)ui << 16);
}
__device__ __forceinline__ unsigned short f2b(float x) {
  __hip_bfloat16 h = __float2bfloat16(x);
  return *(unsigned short*)&h;
}
__device__ __forceinline__ float b2f(unsigned short u) {
  __hip_bfloat16 h = *(__hip_bfloat16*)&u;
  return __bfloat162float(h);
}
__device__ __forceinline__ unsigned int rot16(unsigned int x) {
  return (x >> 16) | (x << 16);
}
// complex-pair fragment transforms
__device__ __forceinline__ bf16x8 xf4(uint4 p, unsigned int x) {
  union { unsigned int u[4]; bf16x8 v; } t;
  t.u[0] = p.x ^ x; t.u[1] = p.y ^ x; t.u[2] = p.z ^ x; t.u[3] = p.w ^ x;
  return t.v;
}
__device__ __forceinline__ bf16x8 xr4(uint4 p, unsigned int x) {
  union { unsigned int u[4]; bf16x8 v; } t;
  t.u[0] = rot16(p.x) ^ x; t.u[1] = rot16(p.y) ^ x;
  t.u[2] = rot16(p.z) ^ x; t.u[3] = rot16(p.w) ^ x;
  return t.v;
}

// ---------------- K0: centered orthonormal DFT matrix, bf16 pairs ----------
__global__ void k_dft(unsigned int* __restrict__ Fbf) {
  int idx = blockIdx.x * blockDim.x + threadIdx.x;
  if (idx >= HW) return;
  int k = idx / WW, n = idx % WW;
  int prod = (k - 160) * (n - 160);
  int r = prod % 320; if (r < 0) r += 320;
  float ang = -6.283185307179586f * (float)r / 320.0f;
  const float s = 0.05590169943749474f; // 1/sqrt(320)
  Fbf[idx] = pack_bf(cosf(ang) * s, sinf(ang) * s);
}

// ---------------- K0b: prepack conv weights (forward, A-operand) -----------
__global__ void k_prep(const float* __restrict__ ck, unsigned int* __restrict__ Wpk) {
  int idx = blockIdx.x * blockDim.x + threadIdx.x;
  if (idx >= 32 * 176) return;
  int o = idx / 176, kw = idx % 176;
  int ky = kw / 16, kx = kw % 16;
  unsigned int v = 0;
  if (kx <= 10) {
    const float* p = &ck[(o * 121 + ky * 11 + kx) * 2];
    v = pack_bf(p[0], p[1]);
  }
  Wpk[idx] = v;
}

// ---------------- K0c: prepack adjoint weights Wt[ch][kx][ky16][o32] -------
__global__ void k_prep2(const float* __restrict__ ck, unsigned short* __restrict__ Wt) {
  int idx = blockIdx.x * blockDim.x + threadIdx.x;
  if (idx >= 2 * 11 * 16 * 32) return;
  int o = idx & 31;
  int ky = (idx >> 5) & 15;
  int rest = idx >> 9;
  int kx = rest % 11, ch = rest / 11;
  unsigned short v = 0;
  if (ky <= 10) v = f2b(ck[(o * 121 + ky * 11 + kx) * 2 + ch]);
  Wt[idx] = v;
}

// ---------------- K0d: RBF lookup table, bf16, [-2,2], 257 entries ---------
__global__ void k_rbftab(const float* __restrict__ w, const float* __restrict__ mu,
                         const float* __restrict__ sigma, unsigned short* __restrict__ Tab) {
  int o = blockIdx.x;
  int e = threadIdx.x;
  if (e >= TABN + 1) return;
  float v = -2.0f + (float)e * (4.0f / (float)TABN);
  float sg = sigma[0];
  float nInv = -1.0f / (2.0f * sg * sg);
  float acc = 0.f;
  for (int i = 0; i < NK; i++) {
    float d = v - mu[i];
    acc += w[o * NK + i] * __expf(d * d * nInv);
  }
  Tab[o * 260 + e] = f2b(acc);
}

// ---------------- K2: conv(11x11) + RBF(table) via MFMA implicit GEMM ------
__global__ __launch_bounds__(256) void k_conv_rbf_mfma(
    const float* __restrict__ u_t, const unsigned int* __restrict__ Wpk,
    const unsigned short* __restrict__ Tab, unsigned short* __restrict__ fukT) {
  __shared__ unsigned int lW[32 * 180];       // 23040 B
  __shared__ unsigned int tIn[26 * 32];       // 3328 B
  __shared__ unsigned short tab[32 * 260];    // 16640 B
  int n = blockIdx.z;
  int y0 = blockIdx.y * 16, x0 = blockIdx.x * 16;
  int tid = threadIdx.x;
  for (int i = tid; i < 32 * 176; i += 256)
    lW[(i / 176) * 180 + (i % 176)] = Wpk[i];
  {
    const unsigned int* Ts = (const unsigned int*)Tab;
    unsigned int* Td = (unsigned int*)tab;
    for (int i = tid; i < 32 * 130; i += 256) Td[i] = Ts[i];
  }
  for (int i = tid; i < 26 * 32; i += 256) {
    int rr = i >> 5, cc = i & 31;
    unsigned int v = 0;
    if (cc < 26) {
      int py = y0 + rr - 5, px = x0 + cc - 5;
      if (py >= 0 && py < HP && px >= 0 && px < HP) {
        int uy = py - PADN; uy = uy < 0 ? -uy : (uy >= HH ? 2 * (HH - 1) - uy : uy);
        int ux = px - PADN; ux = ux < 0 ? -ux : (ux >= WW ? 2 * (WW - 1) - ux : ux);
        const float* up = &u_t[((n * HH + uy) * WW + ux) * 2];
        v = pack_bf(up[0], up[1]);
      }
    }
    tIn[i] = v;
  }
  __syncthreads();
  int lane = tid & 63, wave = tid >> 6;
  int m16 = lane & 15, kq = lane >> 4;
  const short* lWs = (const short*)lW;
  f32x4 acc[4][2] = {};
  for (int ky = 0; ky < 11; ky++) {
    bf16x8 af0 = *(const bf16x8*)&lWs[m16 * 360 + ky * 32 + kq * 8];
    bf16x8 af1 = *(const bf16x8*)&lWs[(m16 + 16) * 360 + ky * 32 + kq * 8];
    #pragma unroll
    for (int nt = 0; nt < 4; nt++) {
      int rr = wave * 4 + nt + ky;
      int c0 = rr * 32 + m16 + kq * 4;
      union { unsigned int u[4]; bf16x8 v; } bu;
      bu.u[0] = tIn[c0]; bu.u[1] = tIn[c0 + 1];
      bu.u[2] = tIn[c0 + 2]; bu.u[3] = tIn[c0 + 3];
      acc[nt][0] = MFMA16(af0, bu.v, acc[nt][0], 0, 0, 0);
      acc[nt][1] = MFMA16(af1, bu.v, acc[nt][1], 0, 0, 0);
    }
  }
  // RBF via table lookup + lerp. C layout: col=lane&15 (x), row=kq*4+r (o)
  const float tscale = (float)TABN / 4.0f;    // 64 per unit v
  #pragma unroll
  for (int nt = 0; nt < 4; nt++) {
    int Y = y0 + wave * 4 + nt;
    int X = x0 + m16;
    if (Y >= HP || X >= HP) continue;
    #pragma unroll
    for (int mt = 0; mt < 2; mt++) {
      u16x4 pk;
      #pragma unroll
      for (int r = 0; r < 4; r++) {
        float v = acc[nt][mt][r];
        int o = mt * 16 + kq * 4 + r;
        float t = (v + 2.0f) * tscale;
        t = fminf(fmaxf(t, 0.0f), 255.999f);
        int i0 = (int)t;
        float fr = t - (float)i0;
        float a = b2f(tab[o * 260 + i0]);
        float bv = b2f(tab[o * 260 + i0 + 1]);
        pk[r] = f2b(a + (bv - a) * fr);
      }
      *(u16x4*)&fukT[(((size_t)n * HP + Y) * HP + X) * 32 + mt * 16 + kq * 4] = pk;
    }
  }
}

// ---------------- K3: transposed conv via MFMA -----------------------------
__global__ __launch_bounds__(256) void k_convT_mfma(
    const unsigned short* __restrict__ fukT, const unsigned short* __restrict__ Wt,
    float* __restrict__ Ru) {
  __shared__ unsigned short rowBuf[42 * 32];
  __shared__ float accS[16 * 67];
  int n = blockIdx.z;
  int y0 = blockIdx.y * 16, x0 = blockIdx.x * 32;
  int tid = threadIdx.x;
  int lane = tid & 63, wave = tid >> 6;
  int ch = wave >> 1, xh = wave & 1;
  int m16 = lane & 15, kq = lane >> 4;
  bf16x8 afr[11];
  #pragma unroll
  for (int kx = 0; kx < 11; kx++)
    afr[kx] = *(const bf16x8*)&Wt[((ch * 11 + kx) * 16 + m16) * 32 + kq * 8];
  for (int i = tid; i < 16 * 67; i += 256) accS[i] = 0.f;
  int xl = xh * 16 + m16;
  for (int t = 0; t < 26; t++) {
    int r = y0 + 6 + t;
    __syncthreads();
    {
      const unsigned int* src = (const unsigned int*)&fukT[(((size_t)n * HP + r) * HP + x0 + 6) * 32];
      unsigned int* dst = (unsigned int*)rowBuf;
      for (int i = tid; i < 42 * 16; i += 256) dst[i] = src[i];
    }
    __syncthreads();
    f32x4 dacc = {};
    #pragma unroll
    for (int kx = 0; kx < 11; kx++) {
      bf16x8 bfrag = *(const bf16x8*)&rowBuf[(xl + 10 - kx) * 32 + kq * 8];
      dacc = MFMA16(afr[kx], bfrag, dacc, 0, 0, 0);
    }
    #pragma unroll
    for (int rg = 0; rg < 4; rg++) {
      int ky = kq * 4 + rg;
      int y = t + ky - 10;
      if (ky <= 10 && y >= 0 && y < 16)
        accS[y * 67 + xl * 2 + ch] += dacc[rg];
    }
  }
  __syncthreads();
  int chO = tid & 1, xO = (tid >> 1) & 31, yb = tid >> 6;
  #pragma unroll
  for (int q = 0; q < 4; q++) {
    int y = yb + q * 4;
    Ru[(((size_t)n * HH + y0 + y) * WW + x0 + xO) * 2 + chO] = accS[y * 67 + xO * 2 + chO];
  }
}

// ---------------- K4: X0T = (u * coil_sens)^T, bf16 pairs, [b][x][y] -------
// LDS-tiled transpose: coalesced read of u/cs, coalesced transposed write.
__global__ __launch_bounds__(256) void k_umulT(const float* __restrict__ u_t,
                                               const float* __restrict__ cs,
                                               unsigned int* __restrict__ X0T) {
  __shared__ unsigned int t[32 * 33];
  int bc = blockIdx.x;                 // 0..99 tile
  int b = blockIdx.y;                  // 0..59 (n*CC+c)
  int n = b / CC;
  int ty = (bc / 10) * 32, tx = (bc % 10) * 32;
  int r = threadIdx.x >> 5, c = threadIdx.x & 31;
  #pragma unroll
  for (int q = 0; q < 4; q++) {
    int y = ty + r + q * 8, x = tx + c;
    const float* up = &u_t[((size_t)n * HW + (size_t)y * WW + x) * 2];
    const float* cp = &cs[((size_t)b * HW + (size_t)y * WW + x) * 2];
    float ur = up[0], ui = up[1], crr = cp[0], cii = cp[1];
    t[(r + q * 8) * 33 + c] = pack_bf(ur * crr - ui * cii, ur * cii + ui * crr);
  }
  __syncthreads();
  #pragma unroll
  for (int q = 0; q < 4; q++) {
    int xx = r + q * 8;                // local x
    X0T[(size_t)b * HW + (size_t)(tx + xx) * WW + ty + c] = t[c * 33 + xx];
  }
}

// ---------------- K5: fused double complex GEMM (one FFT2 pass) ------------
// MODE 1: P2 = mask .* (F*X0*F - f), written TRANSPOSED [b][x][y]
//   stage1: T = F * X0        (A std cplx: a1=(r,-i), a2=(i,r))
//   stage2: Out = T * F, mode-1 epilogue, LDS-transposed store
// MODE 2: Q = conj(F) * P2 * conj(F), written natural [b][y][x]
//   stage1: T = conj(F)*P2    (a1=(r,i), a2=(-i,r))
//   stage2: Out = T * conj(F) (B ^= 0x80000000)
// B inputs are TRANSPOSED [col][k] so every B fragment is one uint4.
// Stage-2 B = F read as [col][k] via symmetry of the centered DFT matrix.
#define LDB(kc, i) (*(const uint4*)&Bb[(size_t)((i) >> 2) * WW + (kc) * 16 + ((i) & 3) * 4])

template <int MODE>
__global__ __launch_bounds__(512, 4) void k_dcpair(
    const unsigned int* __restrict__ Fbf,
    const unsigned int* __restrict__ Bin,   // [b][col][k] transposed
    const float* __restrict__ mask, const float* __restrict__ fdat,
    unsigned int* __restrict__ Out) {
  // sMem views: stage1 B dbuf 2x[320][20] (12800 w) | T [32][324] (10368 w)
  //             | epilogue transpose [320][33] (10560 w)
  __shared__ unsigned int sMem[12800];
  int bid = blockIdx.x;
  int wg = (bid & 7) * 75 + (bid >> 3);   // XCD swizzle (600 = 8*75, bijective)
  int b = wg / 10, strip = wg % 10;
  int i0 = strip * 32;
  int tid = threadIdx.x;
  int lane = tid & 63, wave = tid >> 6;
  int wr = wave >> 2, wc = wave & 3;      // 2x4 wave grid: 16 rows x 80 cols
  int m16 = lane & 15, kq = lane >> 4;
  int colBase = wc * 80;
  const unsigned int XA1 = (MODE == 1) ? 0x80000000u : 0u;
  const unsigned int XA2 = (MODE == 1) ? 0u : 0x00008000u;
  const unsigned int* Bb = Bin + (size_t)b * HW;
  const unsigned int* Arow = Fbf + (size_t)(i0 + wr * 16 + m16) * WW;

  // ---- stage 1: T = (A-transform F) * B, acc in regs ----
  f32x4 aR[5] = {}, aI[5] = {};
  uint4 p0, p1, p2;
  p0 = LDB(0, tid); p1 = LDB(0, tid + 512);
  if (tid < 256) p2 = LDB(0, tid + 1024);
  uint4 ap = *(const uint4*)&Arow[kq * 4];
  #pragma unroll
  for (int kc = 0; kc < 20; kc++) {
    unsigned int* buf = &sMem[(kc & 1) * 6400];
    __syncthreads();
    *(uint4*)&buf[(tid >> 2) * 20 + (tid & 3) * 4] = p0;
    { int i = tid + 512; *(uint4*)&buf[(i >> 2) * 20 + (i & 3) * 4] = p1; }
    if (tid < 256) { int i = tid + 1024; *(uint4*)&buf[(i >> 2) * 20 + (i & 3) * 4] = p2; }
    __syncthreads();
    bf16x8 a1 = xf4(ap, XA1), a2 = xr4(ap, XA2);
    if (kc < 19) {
      p0 = LDB(kc + 1, tid); p1 = LDB(kc + 1, tid + 512);
      if (tid < 256) p2 = LDB(kc + 1, tid + 1024);
      ap = *(const uint4*)&Arow[(kc + 1) * 16 + kq * 4];
    }
    #pragma unroll
    for (int ct = 0; ct < 5; ct++) {
      bf16x8 bb = *(const bf16x8*)&buf[(colBase + ct * 16 + m16) * 20 + kq * 4];
      aR[ct] = MFMA16(a1, bb, aR[ct], 0, 0, 0);
      aI[ct] = MFMA16(a2, bb, aI[ct], 0, 0, 0);
    }
  }
  // ---- park T in LDS (bf16 pairs), [32][324] ----
  __syncthreads();
  #pragma unroll
  for (int ct = 0; ct < 5; ct++)
    #pragma unroll
    for (int r = 0; r < 4; r++) {
      int trow = wr * 16 + kq * 4 + r;
      int tcol = colBase + ct * 16 + m16;
      sMem[trow * 324 + tcol] = pack_bf(aR[ct][r], aI[ct][r]);
    }
  __syncthreads();

  // ---- stage 2: Out = T * (B-transform F), barrier-free K-loop ----
  f32x4 cR[5] = {}, cI[5] = {};
  int tArow = (wr * 16 + m16) * 324;
  const unsigned int* Fc[5];
  uint4 fp[5];
  #pragma unroll
  for (int ct = 0; ct < 5; ct++) {
    Fc[ct] = Fbf + (size_t)(colBase + ct * 16 + m16) * WW;
    fp[ct] = *(const uint4*)&Fc[ct][kq * 4];
  }
  uint4 tp = *(const uint4*)&sMem[tArow + kq * 4];
  #pragma unroll
  for (int kc = 0; kc < 20; kc++) {
    bf16x8 a1 = xf4(tp, 0x80000000u), a2 = xr4(tp, 0u);
    bf16x8 bcur[5];
    #pragma unroll
    for (int ct = 0; ct < 5; ct++)
      bcur[ct] = (MODE == 2) ? xf4(fp[ct], 0x80000000u) : *(const bf16x8*)&fp[ct];
    if (kc < 19) {
      tp = *(const uint4*)&sMem[tArow + (kc + 1) * 16 + kq * 4];
      #pragma unroll
      for (int ct = 0; ct < 5; ct++)
        fp[ct] = *(const uint4*)&Fc[ct][(kc + 1) * 16 + kq * 4];
    }
    #pragma unroll
    for (int ct = 0; ct < 5; ct++) {
      cR[ct] = MFMA16(a1, bcur[ct], cR[ct], 0, 0, 0);
      cI[ct] = MFMA16(a2, bcur[ct], cI[ct], 0, 0, 0);
    }
  }

  // ---- epilogue ----
  if constexpr (MODE == 1) {
    __syncthreads();   // all waves done reading T before overwrite
    int n = b / CC;
    #pragma unroll
    for (int ct = 0; ct < 5; ct++)
      #pragma unroll
      for (int r = 0; r < 4; r++) {
        int row = i0 + wr * 16 + kq * 4 + r;
        int col = colBase + ct * 16 + m16;
        float m = mask[n * HW + row * WW + col];
        size_t fi = ((size_t)b * HW + (size_t)row * WW + col) * 2;
        float vr = m * (cR[ct][r] - fdat[fi]);
        float vi = m * (cI[ct][r] - fdat[fi + 1]);
        sMem[col * 33 + (row - i0)] = pack_bf(vr, vi);
      }
    __syncthreads();
    for (int i2 = tid; i2 < 320 * 32; i2 += 512) {
      int x = i2 >> 5, y = i2 & 31;
      Out[(size_t)b * HW + (size_t)x * WW + i0 + y] = sMem[x * 33 + y];
    }
  } else {
    #pragma unroll
    for (int ct = 0; ct < 5; ct++)
      #pragma unroll
      for (int r = 0; r < 4; r++) {
        int row = i0 + wr * 16 + kq * 4 + r;
        int col = colBase + ct * 16 + m16;
        Out[(size_t)b * HW + (size_t)row * WW + col] = pack_bf(cR[ct][r], cI[ct][r]);
      }
  }
}

// ---------------- K6: coil-combine with conj(sens), bf16-pair input --------
__global__ void k_coilsum(const unsigned int* __restrict__ Z, const float* __restrict__ cs,
                          float* __restrict__ At) {
  int idx = blockIdx.x * blockDim.x + threadIdx.x;
  if (idx >= NN * HW) return;
  int n = idx / HW, hw = idx % HW;
  float ar = 0.f, ai = 0.f;
  for (int c = 0; c < CC; c++) {
    size_t zi = (size_t)(n * CC + c) * HW + hw;
    unsigned int p = Z[zi];
    float zr = b2f((unsigned short)(p & 0xffff));
    float zim = b2f((unsigned short)(p >> 16));
    float crr = cs[zi * 2], cii = cs[zi * 2 + 1];
    ar += zr * crr + zim * cii;
    ai += zim * crr - zr * cii;
  }
  At[idx * 2] = ar;
  At[idx * 2 + 1] = ai;
}

// ---------------- K7: out = u - Ru/FF - lamb*At ----------------------------
__global__ void k_final(const float* __restrict__ u_t, const float* __restrict__ Ru,
                        const float* __restrict__ At, const float* __restrict__ lamb,
                        float* __restrict__ out) {
  int idx = blockIdx.x * blockDim.x + threadIdx.x;
  if (idx >= NN * HW * 2) return;
  out[idx] = u_t[idx] - Ru[idx] * (1.0f / (float)FF) - lamb[0] * At[idx];
}

extern "C" void kernel_launch(void* const* d_in, const int* in_sizes, int n_in,
                              void* d_out, int out_size, void* d_ws, size_t ws_size,
                              hipStream_t stream) {
  const float* u_t   = (const float*)d_in[0];
  const float* fdat  = (const float*)d_in[1];
  const float* cs    = (const float*)d_in[2];
  const float* mask  = (const float*)d_in[3];
  const float* ck    = (const float*)d_in[4];
  const float* w     = (const float*)d_in[5];
  const float* mu    = (const float*)d_in[6];
  const float* sigma = (const float*)d_in[7];
  const float* lamb  = (const float*)d_in[8];
  float* out = (float*)d_out;

  // ws layout (u32 words):
  //  Fbf @0          102400
  //  Wpk @102400     5760
  //  Wt  @108160     5632
  //  Tab @113792     4160
  //  At  @117952     819200
  //  Ru  @937152     819200
  //  big @1756352    12288000
  //   conv phase: fukT [7485696 w]
  //   DC phase:   X0T @big [6144000] ; P2T @big+6144000 [6144000] ; Q @big (aliases X0T)
  unsigned int* wsw = (unsigned int*)d_ws;
  unsigned int* Fbf = wsw;
  unsigned int* Wpk = wsw + 102400;
  unsigned short* Wt = (unsigned short*)(wsw + 108160);
  unsigned short* Tab = (unsigned short*)(wsw + 113792);
  float* At = (float*)(wsw + 117952);
  float* Ru = (float*)(wsw + 937152);
  unsigned int* big = wsw + 1756352;
  unsigned short* fukT = (unsigned short*)big;
  unsigned int* X0T = big;
  unsigned int* P2T = big + 6144000;
  unsigned int* Q = big;

  k_dft<<<(HW + 255) / 256, 256, 0, stream>>>(Fbf);
  k_prep<<<(32 * 176 + 255) / 256, 256, 0, stream>>>(ck, Wpk);
  k_prep2<<<(2 * 11 * 16 * 32 + 255) / 256, 256, 0, stream>>>(ck, Wt);
  k_rbftab<<<32, 320, 0, stream>>>(w, mu, sigma, Tab);
  k_conv_rbf_mfma<<<dim3(22, 22, NN), 256, 0, stream>>>(u_t, Wpk, Tab, fukT);
  k_convT_mfma<<<dim3(10, 20, NN), 256, 0, stream>>>(fukT, Wt, Ru);
  k_umulT<<<dim3(100, 60), 256, 0, stream>>>(u_t, cs, X0T);
  k_dcpair<1><<<600, 512, 0, stream>>>(Fbf, X0T, mask, fdat, P2T);
  k_dcpair<2><<<600, 512, 0, stream>>>(Fbf, P2T, nullptr, nullptr, Q);
  k_coilsum<<<(NN * HW + 255) / 256, 256, 0, stream>>>(Q, cs, At);
  k_final<<<(NN * HW * 2 + 255) / 256, 256, 0, stream>>>(u_t, Ru, At, lamb, out);
}

// Round 2
// 425.792 us; speedup vs baseline: 1.0767x; 1.0767x over previous
//
#include <hip/hip_runtime.h>
#include <hip/hip_bf16.h>
#include <math.h>

#define NN 4
#define CC 15
#define HH 320
#define WW 320
#define HW (HH*WW)          // 102400
#define FF 32
#define KS 11
#define PADN 11
#define CPAD 5
#define HP 342
#define NK 31
#define NCB (NN*CC)
#define TABN 256            // intervals; 257 entries, stride 260

typedef short bf16x8 __attribute__((ext_vector_type(8)));
typedef float f32x4 __attribute__((ext_vector_type(4)));
typedef unsigned short u16x4 __attribute__((ext_vector_type(4)));

#define MFMA16 __builtin_amdgcn_mfma_f32_16x16x32_bf16

__device__ __forceinline__ unsigned int pack_bf(float r, float i) {
  __hip_bfloat16 hr = __float2bfloat16(r), hi = __float2bfloat16(i);
  unsigned short ur = *(unsigned short*)&hr, ui = *(unsigned short*)&hi;
  return (unsigned int)ur | ((unsigned int)ui << 16);
}
__device__ __forceinline__ unsigned short f2b(float x) {
  __hip_bfloat16 h = __float2bfloat16(x);
  return *(unsigned short*)&h;
}
__device__ __forceinline__ float b2f(unsigned short u) {
  __hip_bfloat16 h = *(__hip_bfloat16*)&u;
  return __bfloat162float(h);
}
__device__ __forceinline__ unsigned int rot16(unsigned int x) {
  return (x >> 16) | (x << 16);
}
// complex-pair fragment transforms
__device__ __forceinline__ bf16x8 xf4(uint4 p, unsigned int x) {
  union { unsigned int u[4]; bf16x8 v; } t;
  t.u[0] = p.x ^ x; t.u[1] = p.y ^ x; t.u[2] = p.z ^ x; t.u[3] = p.w ^ x;
  return t.v;
}
__device__ __forceinline__ bf16x8 xr4(uint4 p, unsigned int x) {
  union { unsigned int u[4]; bf16x8 v; } t;
  t.u[0] = rot16(p.x) ^ x; t.u[1] = rot16(p.y) ^ x;
  t.u[2] = rot16(p.z) ^ x; t.u[3] = rot16(p.w) ^ x;
  return t.v;
}
// fragment-packed index: element [row][col] -> [row>>4][col>>4][row&15][col&15]
__device__ __forceinline__ size_t pk_idx(int row, int col) {
  return (size_t)((row >> 4) * 20 + (col >> 4)) * 256 + (row & 15) * 16 + (col & 15);
}

// ---------------- K0: centered orthonormal DFT matrix, bf16 pairs, PACKED --
__global__ void k_dft(unsigned int* __restrict__ Fpk) {
  int idx = blockIdx.x * blockDim.x + threadIdx.x;
  if (idx >= HW) return;
  int k = idx / WW, n = idx % WW;
  int prod = (k - 160) * (n - 160);
  int r = prod % 320; if (r < 0) r += 320;
  float ang = -6.283185307179586f * (float)r / 320.0f;
  const float s = 0.05590169943749474f; // 1/sqrt(320)
  Fpk[pk_idx(k, n)] = pack_bf(cosf(ang) * s, sinf(ang) * s);
}

// ---------------- K0b: prepack conv weights (forward, A-operand) -----------
__global__ void k_prep(const float* __restrict__ ck, unsigned int* __restrict__ Wpk) {
  int idx = blockIdx.x * blockDim.x + threadIdx.x;
  if (idx >= 32 * 176) return;
  int o = idx / 176, kw = idx % 176;
  int ky = kw / 16, kx = kw % 16;
  unsigned int v = 0;
  if (kx <= 10) {
    const float* p = &ck[(o * 121 + ky * 11 + kx) * 2];
    v = pack_bf(p[0], p[1]);
  }
  Wpk[idx] = v;
}

// ---------------- K0c: prepack adjoint weights Wt[ch][kx][ky16][o32] -------
__global__ void k_prep2(const float* __restrict__ ck, unsigned short* __restrict__ Wt) {
  int idx = blockIdx.x * blockDim.x + threadIdx.x;
  if (idx >= 2 * 11 * 16 * 32) return;
  int o = idx & 31;
  int ky = (idx >> 5) & 15;
  int rest = idx >> 9;
  int kx = rest % 11, ch = rest / 11;
  unsigned short v = 0;
  if (ky <= 10) v = f2b(ck[(o * 121 + ky * 11 + kx) * 2 + ch]);
  Wt[idx] = v;
}

// ---------------- K0d: RBF lookup table, bf16, [-2,2], 257 entries ---------
__global__ void k_rbftab(const float* __restrict__ w, const float* __restrict__ mu,
                         const float* __restrict__ sigma, unsigned short* __restrict__ Tab) {
  int o = blockIdx.x;
  int e = threadIdx.x;
  if (e >= TABN + 1) return;
  float v = -2.0f + (float)e * (4.0f / (float)TABN);
  float sg = sigma[0];
  float nInv = -1.0f / (2.0f * sg * sg);
  float acc = 0.f;
  for (int i = 0; i < NK; i++) {
    float d = v - mu[i];
    acc += w[o * NK + i] * __expf(d * d * nInv);
  }
  Tab[o * 260 + e] = f2b(acc);
}

// ---------------- K2: conv(11x11) + RBF(table) via MFMA implicit GEMM ------
__global__ __launch_bounds__(256) void k_conv_rbf_mfma(
    const float* __restrict__ u_t, const unsigned int* __restrict__ Wpk,
    const unsigned short* __restrict__ Tab, unsigned short* __restrict__ fukT) {
  __shared__ unsigned int lW[32 * 180];       // 23040 B
  __shared__ unsigned int tIn[26 * 32];       // 3328 B
  __shared__ unsigned short tab[32 * 260];    // 16640 B
  int n = blockIdx.z;
  int y0 = blockIdx.y * 16, x0 = blockIdx.x * 16;
  int tid = threadIdx.x;
  for (int i = tid; i < 32 * 176; i += 256)
    lW[(i / 176) * 180 + (i % 176)] = Wpk[i];
  {
    const unsigned int* Ts = (const unsigned int*)Tab;
    unsigned int* Td = (unsigned int*)tab;
    for (int i = tid; i < 32 * 130; i += 256) Td[i] = Ts[i];
  }
  for (int i = tid; i < 26 * 32; i += 256) {
    int rr = i >> 5, cc = i & 31;
    unsigned int v = 0;
    if (cc < 26) {
      int py = y0 + rr - 5, px = x0 + cc - 5;
      if (py >= 0 && py < HP && px >= 0 && px < HP) {
        int uy = py - PADN; uy = uy < 0 ? -uy : (uy >= HH ? 2 * (HH - 1) - uy : uy);
        int ux = px - PADN; ux = ux < 0 ? -ux : (ux >= WW ? 2 * (WW - 1) - ux : ux);
        const float* up = &u_t[((n * HH + uy) * WW + ux) * 2];
        v = pack_bf(up[0], up[1]);
      }
    }
    tIn[i] = v;
  }
  __syncthreads();
  int lane = tid & 63, wave = tid >> 6;
  int m16 = lane & 15, kq = lane >> 4;
  const short* lWs = (const short*)lW;
  f32x4 acc[4][2] = {};
  for (int ky = 0; ky < 11; ky++) {
    bf16x8 af0 = *(const bf16x8*)&lWs[m16 * 360 + ky * 32 + kq * 8];
    bf16x8 af1 = *(const bf16x8*)&lWs[(m16 + 16) * 360 + ky * 32 + kq * 8];
    #pragma unroll
    for (int nt = 0; nt < 4; nt++) {
      int rr = wave * 4 + nt + ky;
      int c0 = rr * 32 + m16 + kq * 4;
      union { unsigned int u[4]; bf16x8 v; } bu;
      bu.u[0] = tIn[c0]; bu.u[1] = tIn[c0 + 1];
      bu.u[2] = tIn[c0 + 2]; bu.u[3] = tIn[c0 + 3];
      acc[nt][0] = MFMA16(af0, bu.v, acc[nt][0], 0, 0, 0);
      acc[nt][1] = MFMA16(af1, bu.v, acc[nt][1], 0, 0, 0);
    }
  }
  // RBF via table lookup + lerp. C layout: col=lane&15 (x), row=kq*4+r (o)
  const float tscale = (float)TABN / 4.0f;    // 64 per unit v
  #pragma unroll
  for (int nt = 0; nt < 4; nt++) {
    int Y = y0 + wave * 4 + nt;
    int X = x0 + m16;
    if (Y >= HP || X >= HP) continue;
    #pragma unroll
    for (int mt = 0; mt < 2; mt++) {
      u16x4 pk;
      #pragma unroll
      for (int r = 0; r < 4; r++) {
        float v = acc[nt][mt][r];
        int o = mt * 16 + kq * 4 + r;
        float t = (v + 2.0f) * tscale;
        t = fminf(fmaxf(t, 0.0f), 255.999f);
        int i0 = (int)t;
        float fr = t - (float)i0;
        float a = b2f(tab[o * 260 + i0]);
        float bv = b2f(tab[o * 260 + i0 + 1]);
        pk[r] = f2b(a + (bv - a) * fr);
      }
      *(u16x4*)&fukT[(((size_t)n * HP + Y) * HP + X) * 32 + mt * 16 + kq * 4] = pk;
    }
  }
}

// ---------------- K3: transposed conv via MFMA -----------------------------
__global__ __launch_bounds__(256) void k_convT_mfma(
    const unsigned short* __restrict__ fukT, const unsigned short* __restrict__ Wt,
    float* __restrict__ Ru) {
  __shared__ unsigned short rowBuf[42 * 32];
  __shared__ float accS[16 * 67];
  int n = blockIdx.z;
  int y0 = blockIdx.y * 16, x0 = blockIdx.x * 32;
  int tid = threadIdx.x;
  int lane = tid & 63, wave = tid >> 6;
  int ch = wave >> 1, xh = wave & 1;
  int m16 = lane & 15, kq = lane >> 4;
  bf16x8 afr[11];
  #pragma unroll
  for (int kx = 0; kx < 11; kx++)
    afr[kx] = *(const bf16x8*)&Wt[((ch * 11 + kx) * 16 + m16) * 32 + kq * 8];
  for (int i = tid; i < 16 * 67; i += 256) accS[i] = 0.f;
  int xl = xh * 16 + m16;
  for (int t = 0; t < 26; t++) {
    int r = y0 + 6 + t;
    __syncthreads();
    {
      const unsigned int* src = (const unsigned int*)&fukT[(((size_t)n * HP + r) * HP + x0 + 6) * 32];
      unsigned int* dst = (unsigned int*)rowBuf;
      for (int i = tid; i < 42 * 16; i += 256) dst[i] = src[i];
    }
    __syncthreads();
    f32x4 dacc = {};
    #pragma unroll
    for (int kx = 0; kx < 11; kx++) {
      bf16x8 bfrag = *(const bf16x8*)&rowBuf[(xl + 10 - kx) * 32 + kq * 8];
      dacc = MFMA16(afr[kx], bfrag, dacc, 0, 0, 0);
    }
    #pragma unroll
    for (int rg = 0; rg < 4; rg++) {
      int ky = kq * 4 + rg;
      int y = t + ky - 10;
      if (ky <= 10 && y >= 0 && y < 16)
        accS[y * 67 + xl * 2 + ch] += dacc[rg];
    }
  }
  __syncthreads();
  int chO = tid & 1, xO = (tid >> 1) & 31, yb = tid >> 6;
  #pragma unroll
  for (int q = 0; q < 4; q++) {
    int y = yb + q * 4;
    Ru[(((size_t)n * HH + y0 + y) * WW + x0 + xO) * 2 + chO] = accS[y * 67 + xO * 2 + chO];
  }
}

// ---------------- K4: X0T = (u * coil_sens)^T, PACKED fragments ------------
// LDS-tiled transpose: coalesced read of u/cs, packed-fragment write.
__global__ __launch_bounds__(256) void k_umulT(const float* __restrict__ u_t,
                                               const float* __restrict__ cs,
                                               unsigned int* __restrict__ X0T) {
  __shared__ unsigned int t[32 * 33];
  int bc = blockIdx.x;                 // 0..99 tile
  int b = blockIdx.y;                  // 0..59 (n*CC+c)
  int n = b / CC;
  int ty = (bc / 10) * 32, tx = (bc % 10) * 32;
  int r = threadIdx.x >> 5, c = threadIdx.x & 31;
  #pragma unroll
  for (int q = 0; q < 4; q++) {
    int y = ty + r + q * 8, x = tx + c;
    const float* up = &u_t[((size_t)n * HW + (size_t)y * WW + x) * 2];
    const float* cp = &cs[((size_t)b * HW + (size_t)y * WW + x) * 2];
    float ur = up[0], ui = up[1], crr = cp[0], cii = cp[1];
    t[(r + q * 8) * 33 + c] = pack_bf(ur * crr - ui * cii, ur * cii + ui * crr);
  }
  __syncthreads();
  #pragma unroll
  for (int q = 0; q < 4; q++) {
    int xx = r + q * 8;                // local x (transposed row)
    int x = tx + xx, y = ty + c;
    X0T[(size_t)b * HW + pk_idx(x, y)] = t[c * 33 + xx];
  }
}

// ---------------- K5: fused double complex GEMM (one FFT2 pass) ------------
// MODE 1: P2 = mask .* (F*X0*F - f), written TRANSPOSED-PACKED [b][pk(x,y)]
//   stage1: T = F * X0T'      (A std cplx)
//   stage2: Out = T * F, mode-1 epilogue, LDS-transposed packed store
// MODE 2: Q = conj(F) * P2 * conj(F), written natural [b][y][x]
//   stage1: T2 = conj(F)*P2; park conj(T2)
//   stage2: V = conj(T2) * F; Out = conj(V)     [T*conj(F) = conj(conj(T)*F)]
// All global GEMM operands are fragment-packed: every A/B fragment is one
// coalesced uint4 load (64 lanes -> one contiguous 1KB block). No stage-1
// LDS staging, no K-loop barriers. LDS holds only T (stride 340, b128-clean).
template <int MODE>
__global__ __launch_bounds__(512, 4) void k_dcpair(
    const unsigned int* __restrict__ Fpk,   // packed F fragments
    const unsigned int* __restrict__ Bp,    // packed B fragments per batch
    const float* __restrict__ mask, const float* __restrict__ fdat,
    unsigned int* __restrict__ Out) {
  __shared__ unsigned int sMem[32 * 340];   // 43520 B (T park / epilogue xpose)
  int bid = blockIdx.x;
  int wg = (bid & 7) * 75 + (bid >> 3);     // XCD swizzle (600 = 8*75, bijective)
  int b = wg / 10, strip = wg % 10;
  int i0 = strip * 32;
  int tid = threadIdx.x;
  int lane = tid & 63, wave = tid >> 6;
  int wr = wave >> 2, wc = wave & 3;        // 2x4 wave grid: 16 rows x 80 cols
  int m16 = lane & 15, kq = lane >> 4;
  int loff = m16 * 16 + kq * 4;             // lane word offset inside a fragment
  const unsigned int XA1 = (MODE == 1) ? 0x80000000u : 0u;
  const unsigned int XA2 = (MODE == 1) ? 0u : 0x00008000u;

  // ---- stage 1: T = (A-transform F) * B, barrier-free ----
  const unsigned int* Ap = Fpk + (size_t)(strip * 2 + wr) * 5120 + loff;
  const unsigned int* Bb = Bp + (size_t)b * HW + (size_t)(wc * 5) * 5120 + loff;
  f32x4 aR[5] = {}, aI[5] = {};
  uint4 ap = *(const uint4*)&Ap[0];
  uint4 bp[5];
  #pragma unroll
  for (int ct = 0; ct < 5; ct++) bp[ct] = *(const uint4*)&Bb[ct * 5120];
  #pragma unroll
  for (int kc = 0; kc < 20; kc++) {
    bf16x8 a1 = xf4(ap, XA1), a2 = xr4(ap, XA2);
    bf16x8 bcur[5];
    #pragma unroll
    for (int ct = 0; ct < 5; ct++) bcur[ct] = *(const bf16x8*)&bp[ct];
    if (kc < 19) {
      ap = *(const uint4*)&Ap[(kc + 1) * 256];
      #pragma unroll
      for (int ct = 0; ct < 5; ct++)
        bp[ct] = *(const uint4*)&Bb[ct * 5120 + (kc + 1) * 256];
    }
    #pragma unroll
    for (int ct = 0; ct < 5; ct++) {
      aR[ct] = MFMA16(a1, bcur[ct], aR[ct], 0, 0, 0);
      aI[ct] = MFMA16(a2, bcur[ct], aI[ct], 0, 0, 0);
    }
  }
  // ---- park T in LDS (bf16 pairs; conj for MODE 2), [32][340] ----
  #pragma unroll
  for (int ct = 0; ct < 5; ct++)
    #pragma unroll
    for (int r = 0; r < 4; r++) {
      int trow = wr * 16 + kq * 4 + r;
      int tcol = wc * 80 + ct * 16 + m16;
      unsigned int v = pack_bf(aR[ct][r], aI[ct][r]);
      if (MODE == 2) v ^= 0x80000000u;
      sMem[trow * 340 + tcol] = v;
    }
  __syncthreads();

  // ---- stage 2: Out = T * F, barrier-free (B = raw F for both modes) ----
  f32x4 cR[5] = {}, cI[5] = {};
  const unsigned int* Tr = &sMem[(wr * 16 + m16) * 340];
  const unsigned int* Fb = Fpk + (size_t)(wc * 5) * 5120 + loff;
  uint4 tp = *(const uint4*)&Tr[kq * 4];
  uint4 fp[5];
  #pragma unroll
  for (int ct = 0; ct < 5; ct++) fp[ct] = *(const uint4*)&Fb[ct * 5120];
  #pragma unroll
  for (int kc = 0; kc < 20; kc++) {
    bf16x8 a1 = xf4(tp, 0x80000000u), a2 = xr4(tp, 0u);
    bf16x8 bcur[5];
    #pragma unroll
    for (int ct = 0; ct < 5; ct++) bcur[ct] = *(const bf16x8*)&fp[ct];
    if (kc < 19) {
      tp = *(const uint4*)&Tr[(kc + 1) * 16 + kq * 4];
      #pragma unroll
      for (int ct = 0; ct < 5; ct++)
        fp[ct] = *(const uint4*)&Fb[ct * 5120 + (kc + 1) * 256];
    }
    #pragma unroll
    for (int ct = 0; ct < 5; ct++) {
      cR[ct] = MFMA16(a1, bcur[ct], cR[ct], 0, 0, 0);
      cI[ct] = MFMA16(a2, bcur[ct], cI[ct], 0, 0, 0);
    }
  }

  // ---- epilogue ----
  if constexpr (MODE == 1) {
    __syncthreads();   // all waves done reading T before overwrite
    int n = b / CC;
    #pragma unroll
    for (int ct = 0; ct < 5; ct++)
      #pragma unroll
      for (int r = 0; r < 4; r++) {
        int row = i0 + wr * 16 + kq * 4 + r;
        int col = wc * 80 + ct * 16 + m16;
        float m = mask[n * HW + row * WW + col];
        size_t fi = ((size_t)b * HW + (size_t)row * WW + col) * 2;
        float vr = m * (cR[ct][r] - fdat[fi]);
        float vi = m * (cI[ct][r] - fdat[fi + 1]);
        sMem[col * 33 + (row - i0)] = pack_bf(vr, vi);
      }
    __syncthreads();
    for (int i2 = tid; i2 < 320 * 32; i2 += 512) {
      int x = i2 >> 5, yy = i2 & 31;
      Out[(size_t)b * HW + pk_idx(x, i0 + yy)] = sMem[x * 33 + yy];
    }
  } else {
    // natural layout for k_coilsum; conjugate on store
    #pragma unroll
    for (int ct = 0; ct < 5; ct++)
      #pragma unroll
      for (int r = 0; r < 4; r++) {
        int row = i0 + wr * 16 + kq * 4 + r;
        int col = wc * 80 + ct * 16 + m16;
        Out[(size_t)b * HW + (size_t)row * WW + col] =
            pack_bf(cR[ct][r], cI[ct][r]) ^ 0x80000000u;
      }
  }
}

// ---------------- K6: coil-combine with conj(sens), bf16-pair input --------
__global__ void k_coilsum(const unsigned int* __restrict__ Z, const float* __restrict__ cs,
                          float* __restrict__ At) {
  int idx = blockIdx.x * blockDim.x + threadIdx.x;
  if (idx >= NN * HW) return;
  int n = idx / HW, hw = idx % HW;
  float ar = 0.f, ai = 0.f;
  for (int c = 0; c < CC; c++) {
    size_t zi = (size_t)(n * CC + c) * HW + hw;
    unsigned int p = Z[zi];
    float zr = b2f((unsigned short)(p & 0xffff));
    float zim = b2f((unsigned short)(p >> 16));
    float crr = cs[zi * 2], cii = cs[zi * 2 + 1];
    ar += zr * crr + zim * cii;
    ai += zim * crr - zr * cii;
  }
  At[idx * 2] = ar;
  At[idx * 2 + 1] = ai;
}

// ---------------- K7: out = u - Ru/FF - lamb*At ----------------------------
__global__ void k_final(const float* __restrict__ u_t, const float* __restrict__ Ru,
                        const float* __restrict__ At, const float* __restrict__ lamb,
                        float* __restrict__ out) {
  int idx = blockIdx.x * blockDim.x + threadIdx.x;
  if (idx >= NN * HW * 2) return;
  out[idx] = u_t[idx] - Ru[idx] * (1.0f / (float)FF) - lamb[0] * At[idx];
}

extern "C" void kernel_launch(void* const* d_in, const int* in_sizes, int n_in,
                              void* d_out, int out_size, void* d_ws, size_t ws_size,
                              hipStream_t stream) {
  const float* u_t   = (const float*)d_in[0];
  const float* fdat  = (const float*)d_in[1];
  const float* cs    = (const float*)d_in[2];
  const float* mask  = (const float*)d_in[3];
  const float* ck    = (const float*)d_in[4];
  const float* w     = (const float*)d_in[5];
  const float* mu    = (const float*)d_in[6];
  const float* sigma = (const float*)d_in[7];
  const float* lamb  = (const float*)d_in[8];
  float* out = (float*)d_out;

  // ws layout (u32 words):
  //  Fpk @0          102400  (fragment-packed DFT matrix)
  //  Wpk @102400     5760
  //  Wt  @108160     5632
  //  Tab @113792     4160
  //  At  @117952     819200
  //  Ru  @937152     819200
  //  big @1756352    12288000
  //   conv phase: fukT [7485696 w]
  //   DC phase:   X0T @big [6144000] ; P2T @big+6144000 [6144000] ; Q @big
  unsigned int* wsw = (unsigned int*)d_ws;
  unsigned int* Fpk = wsw;
  unsigned int* Wpk = wsw + 102400;
  unsigned short* Wt = (unsigned short*)(wsw + 108160);
  unsigned short* Tab = (unsigned short*)(wsw + 113792);
  float* At = (float*)(wsw + 117952);
  float* Ru = (float*)(wsw + 937152);
  unsigned int* big = wsw + 1756352;
  unsigned short* fukT = (unsigned short*)big;
  unsigned int* X0T = big;
  unsigned int* P2T = big + 6144000;
  unsigned int* Q = big;

  k_dft<<<(HW + 255) / 256, 256, 0, stream>>>(Fpk);
  k_prep<<<(32 * 176 + 255) / 256, 256, 0, stream>>>(ck, Wpk);
  k_prep2<<<(2 * 11 * 16 * 32 + 255) / 256, 256, 0, stream>>>(ck, Wt);
  k_rbftab<<<32, 320, 0, stream>>>(w, mu, sigma, Tab);
  k_conv_rbf_mfma<<<dim3(22, 22, NN), 256, 0, stream>>>(u_t, Wpk, Tab, fukT);
  k_convT_mfma<<<dim3(10, 20, NN), 256, 0, stream>>>(fukT, Wt, Ru);
  k_umulT<<<dim3(100, 60), 256, 0, stream>>>(u_t, cs, X0T);
  k_dcpair<1><<<600, 512, 0, stream>>>(Fpk, X0T, mask, fdat, P2T);
  k_dcpair<2><<<600, 512, 0, stream>>>(Fpk, P2T, nullptr, nullptr, Q);
  k_coilsum<<<(NN * HW + 255) / 256, 256, 0, stream>>>(Q, cs, At);
  k_final<<<(NN * HW * 2 + 255) / 256, 256, 0, stream>>>(u_t, Ru, At, lamb, out);
}

// Round 3
// 424.068 us; speedup vs baseline: 1.0811x; 1.0041x over previous
//
#include <hip/hip_runtime.h>
#include <hip/hip_bf16.h>
#include <math.h>

#define NN 4
#define CC 15
#define HH 320
#define WW 320
#define HW (HH*WW)          // 102400
#define FF 32
#define KS 11
#define PADN 11
#define CPAD 5
#define HP 342
#define NK 31
#define NCB (NN*CC)
#define TABN 256            // intervals; 257 entries, stride 260

typedef short bf16x8 __attribute__((ext_vector_type(8)));
typedef float f32x4 __attribute__((ext_vector_type(4)));
typedef unsigned short u16x4 __attribute__((ext_vector_type(4)));

#define MFMA16 __builtin_amdgcn_mfma_f32_16x16x32_bf16

__device__ __forceinline__ unsigned int pack_bf(float r, float i) {
  __hip_bfloat16 hr = __float2bfloat16(r), hi = __float2bfloat16(i);
  unsigned short ur = *(unsigned short*)&hr, ui = *(unsigned short*)&hi;
  return (unsigned int)ur | ((unsigned int)ui << 16);
}
__device__ __forceinline__ unsigned short f2b(float x) {
  __hip_bfloat16 h = __float2bfloat16(x);
  return *(unsigned short*)&h;
}
__device__ __forceinline__ float b2f(unsigned short u) {
  __hip_bfloat16 h = *(__hip_bfloat16*)&u;
  return __bfloat162float(h);
}
__device__ __forceinline__ unsigned int rot16(unsigned int x) {
  return (x >> 16) | (x << 16);
}
// complex-pair fragment transforms
__device__ __forceinline__ bf16x8 xf4(uint4 p, unsigned int x) {
  union { unsigned int u[4]; bf16x8 v; } t;
  t.u[0] = p.x ^ x; t.u[1] = p.y ^ x; t.u[2] = p.z ^ x; t.u[3] = p.w ^ x;
  return t.v;
}
__device__ __forceinline__ bf16x8 xr4(uint4 p, unsigned int x) {
  union { unsigned int u[4]; bf16x8 v; } t;
  t.u[0] = rot16(p.x) ^ x; t.u[1] = rot16(p.y) ^ x;
  t.u[2] = rot16(p.z) ^ x; t.u[3] = rot16(p.w) ^ x;
  return t.v;
}
// fragment-packed index: element [row][col] -> [row>>4][col>>4][row&15][col&15]
__device__ __forceinline__ size_t pk_idx(int row, int col) {
  return (size_t)((row >> 4) * 20 + (col >> 4)) * 256 + (row & 15) * 16 + (col & 15);
}

// ---------------- K0: centered orthonormal DFT matrix, bf16 pairs, PACKED --
__global__ void k_dft(unsigned int* __restrict__ Fpk) {
  int idx = blockIdx.x * blockDim.x + threadIdx.x;
  if (idx >= HW) return;
  int k = idx / WW, n = idx % WW;
  int prod = (k - 160) * (n - 160);
  int r = prod % 320; if (r < 0) r += 320;
  float ang = -6.283185307179586f * (float)r / 320.0f;
  const float s = 0.05590169943749474f; // 1/sqrt(320)
  Fpk[pk_idx(k, n)] = pack_bf(cosf(ang) * s, sinf(ang) * s);
}

// ---------------- K0b: prepack conv weights (forward, A-operand) -----------
__global__ void k_prep(const float* __restrict__ ck, unsigned int* __restrict__ Wpk) {
  int idx = blockIdx.x * blockDim.x + threadIdx.x;
  if (idx >= 32 * 176) return;
  int o = idx / 176, kw = idx % 176;
  int ky = kw / 16, kx = kw % 16;
  unsigned int v = 0;
  if (kx <= 10) {
    const float* p = &ck[(o * 121 + ky * 11 + kx) * 2];
    v = pack_bf(p[0], p[1]);
  }
  Wpk[idx] = v;
}

// ---------------- K0c: prepack adjoint weights Wt[ch][kx][ky16][o32] -------
__global__ void k_prep2(const float* __restrict__ ck, unsigned short* __restrict__ Wt) {
  int idx = blockIdx.x * blockDim.x + threadIdx.x;
  if (idx >= 2 * 11 * 16 * 32) return;
  int o = idx & 31;
  int ky = (idx >> 5) & 15;
  int rest = idx >> 9;
  int kx = rest % 11, ch = rest / 11;
  unsigned short v = 0;
  if (ky <= 10) v = f2b(ck[(o * 121 + ky * 11 + kx) * 2 + ch]);
  Wt[idx] = v;
}

// ---------------- K0d: RBF lookup table, bf16, [-2,2], 257 entries ---------
__global__ void k_rbftab(const float* __restrict__ w, const float* __restrict__ mu,
                         const float* __restrict__ sigma, unsigned short* __restrict__ Tab) {
  int o = blockIdx.x;
  int e = threadIdx.x;
  if (e >= TABN + 1) return;
  float v = -2.0f + (float)e * (4.0f / (float)TABN);
  float sg = sigma[0];
  float nInv = -1.0f / (2.0f * sg * sg);
  float acc = 0.f;
  for (int i = 0; i < NK; i++) {
    float d = v - mu[i];
    acc += w[o * NK + i] * __expf(d * d * nInv);
  }
  Tab[o * 260 + e] = f2b(acc);
}

// ---------------- K2: conv(11x11) + RBF(table) via MFMA implicit GEMM ------
__global__ __launch_bounds__(256) void k_conv_rbf_mfma(
    const float* __restrict__ u_t, const unsigned int* __restrict__ Wpk,
    const unsigned short* __restrict__ Tab, unsigned short* __restrict__ fukT) {
  __shared__ unsigned int lW[32 * 180];       // 23040 B
  __shared__ unsigned int tIn[26 * 32];       // 3328 B
  __shared__ unsigned short tab[32 * 260];    // 16640 B
  int n = blockIdx.z;
  int y0 = blockIdx.y * 16, x0 = blockIdx.x * 16;
  int tid = threadIdx.x;
  for (int i = tid; i < 32 * 176; i += 256)
    lW[(i / 176) * 180 + (i % 176)] = Wpk[i];
  {
    const unsigned int* Ts = (const unsigned int*)Tab;
    unsigned int* Td = (unsigned int*)tab;
    for (int i = tid; i < 32 * 130; i += 256) Td[i] = Ts[i];
  }
  for (int i = tid; i < 26 * 32; i += 256) {
    int rr = i >> 5, cc = i & 31;
    unsigned int v = 0;
    if (cc < 26) {
      int py = y0 + rr - 5, px = x0 + cc - 5;
      if (py >= 0 && py < HP && px >= 0 && px < HP) {
        int uy = py - PADN; uy = uy < 0 ? -uy : (uy >= HH ? 2 * (HH - 1) - uy : uy);
        int ux = px - PADN; ux = ux < 0 ? -ux : (ux >= WW ? 2 * (WW - 1) - ux : ux);
        const float* up = &u_t[((n * HH + uy) * WW + ux) * 2];
        v = pack_bf(up[0], up[1]);
      }
    }
    tIn[i] = v;
  }
  __syncthreads();
  int lane = tid & 63, wave = tid >> 6;
  int m16 = lane & 15, kq = lane >> 4;
  const short* lWs = (const short*)lW;
  f32x4 acc[4][2] = {};
  for (int ky = 0; ky < 11; ky++) {
    bf16x8 af0 = *(const bf16x8*)&lWs[m16 * 360 + ky * 32 + kq * 8];
    bf16x8 af1 = *(const bf16x8*)&lWs[(m16 + 16) * 360 + ky * 32 + kq * 8];
    #pragma unroll
    for (int nt = 0; nt < 4; nt++) {
      int rr = wave * 4 + nt + ky;
      int c0 = rr * 32 + m16 + kq * 4;
      union { unsigned int u[4]; bf16x8 v; } bu;
      bu.u[0] = tIn[c0]; bu.u[1] = tIn[c0 + 1];
      bu.u[2] = tIn[c0 + 2]; bu.u[3] = tIn[c0 + 3];
      acc[nt][0] = MFMA16(af0, bu.v, acc[nt][0], 0, 0, 0);
      acc[nt][1] = MFMA16(af1, bu.v, acc[nt][1], 0, 0, 0);
    }
  }
  // RBF via table lookup + lerp. C layout: col=lane&15 (x), row=kq*4+r (o)
  const float tscale = (float)TABN / 4.0f;    // 64 per unit v
  #pragma unroll
  for (int nt = 0; nt < 4; nt++) {
    int Y = y0 + wave * 4 + nt;
    int X = x0 + m16;
    if (Y >= HP || X >= HP) continue;
    #pragma unroll
    for (int mt = 0; mt < 2; mt++) {
      u16x4 pk;
      #pragma unroll
      for (int r = 0; r < 4; r++) {
        float v = acc[nt][mt][r];
        int o = mt * 16 + kq * 4 + r;
        float t = (v + 2.0f) * tscale;
        t = fminf(fmaxf(t, 0.0f), 255.999f);
        int i0 = (int)t;
        float fr = t - (float)i0;
        float a = b2f(tab[o * 260 + i0]);
        float bv = b2f(tab[o * 260 + i0 + 1]);
        pk[r] = f2b(a + (bv - a) * fr);
      }
      *(u16x4*)&fukT[(((size_t)n * HP + Y) * HP + X) * 32 + mt * 16 + kq * 4] = pk;
    }
  }
}

// ---------------- K3: transposed conv via MFMA -----------------------------
__global__ __launch_bounds__(256) void k_convT_mfma(
    const unsigned short* __restrict__ fukT, const unsigned short* __restrict__ Wt,
    float* __restrict__ Ru) {
  __shared__ unsigned short rowBuf[42 * 32];
  __shared__ float accS[16 * 67];
  int n = blockIdx.z;
  int y0 = blockIdx.y * 16, x0 = blockIdx.x * 32;
  int tid = threadIdx.x;
  int lane = tid & 63, wave = tid >> 6;
  int ch = wave >> 1, xh = wave & 1;
  int m16 = lane & 15, kq = lane >> 4;
  bf16x8 afr[11];
  #pragma unroll
  for (int kx = 0; kx < 11; kx++)
    afr[kx] = *(const bf16x8*)&Wt[((ch * 11 + kx) * 16 + m16) * 32 + kq * 8];
  for (int i = tid; i < 16 * 67; i += 256) accS[i] = 0.f;
  int xl = xh * 16 + m16;
  for (int t = 0; t < 26; t++) {
    int r = y0 + 6 + t;
    __syncthreads();
    {
      const unsigned int* src = (const unsigned int*)&fukT[(((size_t)n * HP + r) * HP + x0 + 6) * 32];
      unsigned int* dst = (unsigned int*)rowBuf;
      for (int i = tid; i < 42 * 16; i += 256) dst[i] = src[i];
    }
    __syncthreads();
    f32x4 dacc = {};
    #pragma unroll
    for (int kx = 0; kx < 11; kx++) {
      bf16x8 bfrag = *(const bf16x8*)&rowBuf[(xl + 10 - kx) * 32 + kq * 8];
      dacc = MFMA16(afr[kx], bfrag, dacc, 0, 0, 0);
    }
    #pragma unroll
    for (int rg = 0; rg < 4; rg++) {
      int ky = kq * 4 + rg;
      int y = t + ky - 10;
      if (ky <= 10 && y >= 0 && y < 16)
        accS[y * 67 + xl * 2 + ch] += dacc[rg];
    }
  }
  __syncthreads();
  int chO = tid & 1, xO = (tid >> 1) & 31, yb = tid >> 6;
  #pragma unroll
  for (int q = 0; q < 4; q++) {
    int y = yb + q * 4;
    Ru[(((size_t)n * HH + y0 + y) * WW + x0 + xO) * 2 + chO] = accS[y * 67 + xO * 2 + chO];
  }
}

// ---------------- K4: X0T = (u * coil_sens)^T, PACKED fragments ------------
__global__ __launch_bounds__(256) void k_umulT(const float* __restrict__ u_t,
                                               const float* __restrict__ cs,
                                               unsigned int* __restrict__ X0T) {
  __shared__ unsigned int t[32 * 33];
  int bc = blockIdx.x;                 // 0..99 tile
  int b = blockIdx.y;                  // 0..59 (n*CC+c)
  int n = b / CC;
  int ty = (bc / 10) * 32, tx = (bc % 10) * 32;
  int r = threadIdx.x >> 5, c = threadIdx.x & 31;
  #pragma unroll
  for (int q = 0; q < 4; q++) {
    int y = ty + r + q * 8, x = tx + c;
    const float* up = &u_t[((size_t)n * HW + (size_t)y * WW + x) * 2];
    const float* cp = &cs[((size_t)b * HW + (size_t)y * WW + x) * 2];
    float ur = up[0], ui = up[1], crr = cp[0], cii = cp[1];
    t[(r + q * 8) * 33 + c] = pack_bf(ur * crr - ui * cii, ur * cii + ui * crr);
  }
  __syncthreads();
  #pragma unroll
  for (int q = 0; q < 4; q++) {
    int xx = r + q * 8;                // local x (transposed row)
    int x = tx + xx, y = ty + c;
    X0T[(size_t)b * HW + pk_idx(x, y)] = t[c * 33 + xx];
  }
}

// ---------------- K5: fused double complex GEMM (one FFT2 pass) ------------
// 16-row strips, 4 waves/block, 1200 blocks. Barrier-free K-loops; all
// operands fragment-packed (1 uint4 load per fragment). Depth-2 register
// prefetch in stage 1 (the long-latency stream). LDS: T park [16][340]
// aliased with mode-1 transpose buffer [320][17] (21.8 KB).
// MODE 1: P2 = mask .* (F*X0*F - f), written TRANSPOSED-PACKED
// MODE 2: Q = conj(F)*P2*conj(F) = conj(conj(T)*F), T = conj(F)*P2; natural out
template <int MODE>
__global__ __launch_bounds__(256, 4) void k_dcpair(
    const unsigned int* __restrict__ Fpk,   // packed F fragments
    const unsigned int* __restrict__ Bp,    // packed B fragments per batch
    const float* __restrict__ mask, const float* __restrict__ fdat,
    unsigned int* __restrict__ Out) {
  __shared__ unsigned int sMem[5440];       // 21760 B
  int bid = blockIdx.x;
  int wg = (bid & 7) * 150 + (bid >> 3);    // XCD swizzle (1200 = 8*150)
  int b = wg / 20, strip = wg % 20;
  int i0 = strip * 16;
  int tid = threadIdx.x;
  int lane = tid & 63, wc = tid >> 6;       // 4 waves = 4 col groups of 80
  int m16 = lane & 15, kq = lane >> 4;
  int loff = m16 * 16 + kq * 4;             // lane word offset inside fragment
  const unsigned int XA1 = (MODE == 1) ? 0x80000000u : 0u;
  const unsigned int XA2 = (MODE == 1) ? 0u : 0x00008000u;

  const unsigned int* Ap = Fpk + (size_t)strip * 5120 + loff;
  const unsigned int* Bb = Bp + (size_t)b * HW + (size_t)(wc * 5) * 5120 + loff;

  // ---- stage 1: T = (A-transform F) * B, depth-2 prefetch, barrier-free ----
  f32x4 aR[5] = {}, aI[5] = {};
  uint4 a0 = *(const uint4*)&Ap[0];
  uint4 a1v = *(const uint4*)&Ap[256];
  uint4 b0[5], b1[5];
  #pragma unroll
  for (int ct = 0; ct < 5; ct++) {
    b0[ct] = *(const uint4*)&Bb[ct * 5120];
    b1[ct] = *(const uint4*)&Bb[ct * 5120 + 256];
  }
  #pragma unroll
  for (int kc2 = 0; kc2 < 10; kc2++) {
    {  // even step: kc = 2*kc2 (uses set 0, reloads kc+2)
      const int kc = kc2 * 2;
      bf16x8 x1 = xf4(a0, XA1), x2 = xr4(a0, XA2);
      bf16x8 bc[5];
      #pragma unroll
      for (int ct = 0; ct < 5; ct++) bc[ct] = *(const bf16x8*)&b0[ct];
      if (kc + 2 < 20) {
        a0 = *(const uint4*)&Ap[(kc + 2) * 256];
        #pragma unroll
        for (int ct = 0; ct < 5; ct++)
          b0[ct] = *(const uint4*)&Bb[ct * 5120 + (kc + 2) * 256];
      }
      #pragma unroll
      for (int ct = 0; ct < 5; ct++) {
        aR[ct] = MFMA16(x1, bc[ct], aR[ct], 0, 0, 0);
        aI[ct] = MFMA16(x2, bc[ct], aI[ct], 0, 0, 0);
      }
    }
    {  // odd step: kc = 2*kc2+1 (uses set 1, reloads kc+2)
      const int kc = kc2 * 2 + 1;
      bf16x8 x1 = xf4(a1v, XA1), x2 = xr4(a1v, XA2);
      bf16x8 bc[5];
      #pragma unroll
      for (int ct = 0; ct < 5; ct++) bc[ct] = *(const bf16x8*)&b1[ct];
      if (kc + 2 < 20) {
        a1v = *(const uint4*)&Ap[(kc + 2) * 256];
        #pragma unroll
        for (int ct = 0; ct < 5; ct++)
          b1[ct] = *(const uint4*)&Bb[ct * 5120 + (kc + 2) * 256];
      }
      #pragma unroll
      for (int ct = 0; ct < 5; ct++) {
        aR[ct] = MFMA16(x1, bc[ct], aR[ct], 0, 0, 0);
        aI[ct] = MFMA16(x2, bc[ct], aI[ct], 0, 0, 0);
      }
    }
  }
  // ---- park T in LDS (bf16 pairs; conj for MODE 2), [16][340] ----
  #pragma unroll
  for (int ct = 0; ct < 5; ct++)
    #pragma unroll
    for (int r = 0; r < 4; r++) {
      int trow = kq * 4 + r;
      int tcol = wc * 80 + ct * 16 + m16;
      unsigned int v = pack_bf(aR[ct][r], aI[ct][r]);
      if (MODE == 2) v ^= 0x80000000u;
      sMem[trow * 340 + tcol] = v;
    }
  __syncthreads();

  // ---- stage 2: Out = T * F, barrier-free (B = raw F for both modes) ----
  f32x4 cR[5] = {}, cI[5] = {};
  const unsigned int* Tr = &sMem[m16 * 340];
  const unsigned int* Fb = Fpk + (size_t)(wc * 5) * 5120 + loff;
  uint4 tp = *(const uint4*)&Tr[kq * 4];
  uint4 fp[5];
  #pragma unroll
  for (int ct = 0; ct < 5; ct++) fp[ct] = *(const uint4*)&Fb[ct * 5120];
  #pragma unroll
  for (int kc = 0; kc < 20; kc++) {
    bf16x8 x1 = xf4(tp, 0x80000000u), x2 = xr4(tp, 0u);
    bf16x8 bc[5];
    #pragma unroll
    for (int ct = 0; ct < 5; ct++) bc[ct] = *(const bf16x8*)&fp[ct];
    if (kc < 19) {
      tp = *(const uint4*)&Tr[(kc + 1) * 16 + kq * 4];
      #pragma unroll
      for (int ct = 0; ct < 5; ct++)
        fp[ct] = *(const uint4*)&Fb[ct * 5120 + (kc + 1) * 256];
    }
    #pragma unroll
    for (int ct = 0; ct < 5; ct++) {
      cR[ct] = MFMA16(x1, bc[ct], cR[ct], 0, 0, 0);
      cI[ct] = MFMA16(x2, bc[ct], cI[ct], 0, 0, 0);
    }
  }

  // ---- epilogue ----
  if constexpr (MODE == 1) {
    __syncthreads();   // all waves done reading T before overwrite
    int n = b / CC;
    #pragma unroll
    for (int ct = 0; ct < 5; ct++)
      #pragma unroll
      for (int r = 0; r < 4; r++) {
        int row = i0 + kq * 4 + r;
        int col = wc * 80 + ct * 16 + m16;
        float m = mask[n * HW + row * WW + col];
        size_t fi = ((size_t)b * HW + (size_t)row * WW + col) * 2;
        float vr = m * (cR[ct][r] - fdat[fi]);
        float vi = m * (cI[ct][r] - fdat[fi + 1]);
        sMem[col * 17 + kq * 4 + r] = pack_bf(vr, vi);
      }
    __syncthreads();
    for (int i2 = tid; i2 < 320 * 16; i2 += 256) {
      int x = i2 >> 4, yy = i2 & 15;
      Out[(size_t)b * HW + pk_idx(x, i0 + yy)] = sMem[x * 17 + yy];
    }
  } else {
    // natural layout for k_coilsum; conjugate on store
    #pragma unroll
    for (int ct = 0; ct < 5; ct++)
      #pragma unroll
      for (int r = 0; r < 4; r++) {
        int row = i0 + kq * 4 + r;
        int col = wc * 80 + ct * 16 + m16;
        Out[(size_t)b * HW + (size_t)row * WW + col] =
            pack_bf(cR[ct][r], cI[ct][r]) ^ 0x80000000u;
      }
  }
}

// ---------------- K6: coil-combine with conj(sens), bf16-pair input --------
__global__ void k_coilsum(const unsigned int* __restrict__ Z, const float* __restrict__ cs,
                          float* __restrict__ At) {
  int idx = blockIdx.x * blockDim.x + threadIdx.x;
  if (idx >= NN * HW) return;
  int n = idx / HW, hw = idx % HW;
  float ar = 0.f, ai = 0.f;
  for (int c = 0; c < CC; c++) {
    size_t zi = (size_t)(n * CC + c) * HW + hw;
    unsigned int p = Z[zi];
    float zr = b2f((unsigned short)(p & 0xffff));
    float zim = b2f((unsigned short)(p >> 16));
    float crr = cs[zi * 2], cii = cs[zi * 2 + 1];
    ar += zr * crr + zim * cii;
    ai += zim * crr - zr * cii;
  }
  At[idx * 2] = ar;
  At[idx * 2 + 1] = ai;
}

// ---------------- K7: out = u - Ru/FF - lamb*At ----------------------------
__global__ void k_final(const float* __restrict__ u_t, const float* __restrict__ Ru,
                        const float* __restrict__ At, const float* __restrict__ lamb,
                        float* __restrict__ out) {
  int idx = blockIdx.x * blockDim.x + threadIdx.x;
  if (idx >= NN * HW * 2) return;
  out[idx] = u_t[idx] - Ru[idx] * (1.0f / (float)FF) - lamb[0] * At[idx];
}

extern "C" void kernel_launch(void* const* d_in, const int* in_sizes, int n_in,
                              void* d_out, int out_size, void* d_ws, size_t ws_size,
                              hipStream_t stream) {
  const float* u_t   = (const float*)d_in[0];
  const float* fdat  = (const float*)d_in[1];
  const float* cs    = (const float*)d_in[2];
  const float* mask  = (const float*)d_in[3];
  const float* ck    = (const float*)d_in[4];
  const float* w     = (const float*)d_in[5];
  const float* mu    = (const float*)d_in[6];
  const float* sigma = (const float*)d_in[7];
  const float* lamb  = (const float*)d_in[8];
  float* out = (float*)d_out;

  // ws layout (u32 words):
  //  Fpk @0          102400  (fragment-packed DFT matrix)
  //  Wpk @102400     5760
  //  Wt  @108160     5632
  //  Tab @113792     4160
  //  At  @117952     819200
  //  Ru  @937152     819200
  //  big @1756352    12288000
  //   conv phase: fukT [7485696 w]
  //   DC phase:   X0T @big [6144000] ; P2T @big+6144000 [6144000] ; Q @big
  unsigned int* wsw = (unsigned int*)d_ws;
  unsigned int* Fpk = wsw;
  unsigned int* Wpk = wsw + 102400;
  unsigned short* Wt = (unsigned short*)(wsw + 108160);
  unsigned short* Tab = (unsigned short*)(wsw + 113792);
  float* At = (float*)(wsw + 117952);
  float* Ru = (float*)(wsw + 937152);
  unsigned int* big = wsw + 1756352;
  unsigned short* fukT = (unsigned short*)big;
  unsigned int* X0T = big;
  unsigned int* P2T = big + 6144000;
  unsigned int* Q = big;

  k_dft<<<(HW + 255) / 256, 256, 0, stream>>>(Fpk);
  k_prep<<<(32 * 176 + 255) / 256, 256, 0, stream>>>(ck, Wpk);
  k_prep2<<<(2 * 11 * 16 * 32 + 255) / 256, 256, 0, stream>>>(ck, Wt);
  k_rbftab<<<32, 320, 0, stream>>>(w, mu, sigma, Tab);
  k_conv_rbf_mfma<<<dim3(22, 22, NN), 256, 0, stream>>>(u_t, Wpk, Tab, fukT);
  k_convT_mfma<<<dim3(10, 20, NN), 256, 0, stream>>>(fukT, Wt, Ru);
  k_umulT<<<dim3(100, 60), 256, 0, stream>>>(u_t, cs, X0T);
  k_dcpair<1><<<1200, 256, 0, stream>>>(Fpk, X0T, mask, fdat, P2T);
  k_dcpair<2><<<1200, 256, 0, stream>>>(Fpk, P2T, nullptr, nullptr, Q);
  k_coilsum<<<(NN * HW + 255) / 256, 256, 0, stream>>>(Q, cs, At);
  k_final<<<(NN * HW * 2 + 255) / 256, 256, 0, stream>>>(u_t, Ru, At, lamb, out);
}

// Round 4
// 388.747 us; speedup vs baseline: 1.1793x; 1.0909x over previous
//
#include <hip/hip_runtime.h>
#include <hip/hip_bf16.h>
#include <math.h>

#define NN 4
#define CC 15
#define HH 320
#define WW 320
#define HW (HH*WW)          // 102400
#define FF 32
#define KS 11
#define PADN 11
#define CPAD 5
#define HP 342
#define NK 31
#define NCB (NN*CC)
#define TABN 256            // intervals; 257 entries, stride 260

typedef short bf16x8 __attribute__((ext_vector_type(8)));
typedef float f32x4 __attribute__((ext_vector_type(4)));
typedef unsigned short u16x4 __attribute__((ext_vector_type(4)));

#define MFMA16 __builtin_amdgcn_mfma_f32_16x16x32_bf16

__device__ __forceinline__ unsigned int pack_bf(float r, float i) {
  __hip_bfloat16 hr = __float2bfloat16(r), hi = __float2bfloat16(i);
  unsigned short ur = *(unsigned short*)&hr, ui = *(unsigned short*)&hi;
  return (unsigned int)ur | ((unsigned int)ui << 16);
}
__device__ __forceinline__ unsigned short f2b(float x) {
  __hip_bfloat16 h = __float2bfloat16(x);
  return *(unsigned short*)&h;
}
__device__ __forceinline__ float b2f(unsigned short u) {
  __hip_bfloat16 h = *(__hip_bfloat16*)&u;
  return __bfloat162float(h);
}
__device__ __forceinline__ unsigned int rot16(unsigned int x) {
  return (x >> 16) | (x << 16);
}
// complex-pair fragment transforms
__device__ __forceinline__ bf16x8 xf4(uint4 p, unsigned int x) {
  union { unsigned int u[4]; bf16x8 v; } t;
  t.u[0] = p.x ^ x; t.u[1] = p.y ^ x; t.u[2] = p.z ^ x; t.u[3] = p.w ^ x;
  return t.v;
}
__device__ __forceinline__ bf16x8 xr4(uint4 p, unsigned int x) {
  union { unsigned int u[4]; bf16x8 v; } t;
  t.u[0] = rot16(p.x) ^ x; t.u[1] = rot16(p.y) ^ x;
  t.u[2] = rot16(p.z) ^ x; t.u[3] = rot16(p.w) ^ x;
  return t.v;
}
// fragment-packed index: element [row][col] -> [row>>4][col>>4][row&15][col&15]
__device__ __forceinline__ size_t pk_idx(int row, int col) {
  return (size_t)((row >> 4) * 20 + (col >> 4)) * 256 + (row & 15) * 16 + (col & 15);
}

// ---------------- K0: centered orthonormal DFT matrix, bf16 pairs, PACKED --
__global__ void k_dft(unsigned int* __restrict__ Fpk) {
  int idx = blockIdx.x * blockDim.x + threadIdx.x;
  if (idx >= HW) return;
  int k = idx / WW, n = idx % WW;
  int prod = (k - 160) * (n - 160);
  int r = prod % 320; if (r < 0) r += 320;
  float ang = -6.283185307179586f * (float)r / 320.0f;
  const float s = 0.05590169943749474f; // 1/sqrt(320)
  Fpk[pk_idx(k, n)] = pack_bf(cosf(ang) * s, sinf(ang) * s);
}

// ---------------- K0b: prepack conv weights (forward, A-operand) -----------
__global__ void k_prep(const float* __restrict__ ck, unsigned int* __restrict__ Wpk) {
  int idx = blockIdx.x * blockDim.x + threadIdx.x;
  if (idx >= 32 * 176) return;
  int o = idx / 176, kw = idx % 176;
  int ky = kw / 16, kx = kw % 16;
  unsigned int v = 0;
  if (kx <= 10) {
    const float* p = &ck[(o * 121 + ky * 11 + kx) * 2];
    v = pack_bf(p[0], p[1]);
  }
  Wpk[idx] = v;
}

// ---------------- K0c: prepack adjoint weights Wt[ch][kx][ky16][o32] -------
__global__ void k_prep2(const float* __restrict__ ck, unsigned short* __restrict__ Wt) {
  int idx = blockIdx.x * blockDim.x + threadIdx.x;
  if (idx >= 2 * 11 * 16 * 32) return;
  int o = idx & 31;
  int ky = (idx >> 5) & 15;
  int rest = idx >> 9;
  int kx = rest % 11, ch = rest / 11;
  unsigned short v = 0;
  if (ky <= 10) v = f2b(ck[(o * 121 + ky * 11 + kx) * 2 + ch]);
  Wt[idx] = v;
}

// ---------------- K0d: RBF lookup table, bf16, [-2,2], 257 entries ---------
__global__ void k_rbftab(const float* __restrict__ w, const float* __restrict__ mu,
                         const float* __restrict__ sigma, unsigned short* __restrict__ Tab) {
  int o = blockIdx.x;
  int e = threadIdx.x;
  if (e >= TABN + 1) return;
  float v = -2.0f + (float)e * (4.0f / (float)TABN);
  float sg = sigma[0];
  float nInv = -1.0f / (2.0f * sg * sg);
  float acc = 0.f;
  for (int i = 0; i < NK; i++) {
    float d = v - mu[i];
    acc += w[o * NK + i] * __expf(d * d * nInv);
  }
  Tab[o * 260 + e] = f2b(acc);
}

// ---------------- K2: conv(11x11) + RBF(table) via MFMA implicit GEMM ------
__global__ __launch_bounds__(256) void k_conv_rbf_mfma(
    const float* __restrict__ u_t, const unsigned int* __restrict__ Wpk,
    const unsigned short* __restrict__ Tab, unsigned short* __restrict__ fukT) {
  __shared__ unsigned int lW[32 * 180];       // 23040 B
  __shared__ unsigned int tIn[26 * 32];       // 3328 B
  __shared__ unsigned short tab[32 * 260];    // 16640 B
  int n = blockIdx.z;
  int y0 = blockIdx.y * 16, x0 = blockIdx.x * 16;
  int tid = threadIdx.x;
  for (int i = tid; i < 32 * 176; i += 256)
    lW[(i / 176) * 180 + (i % 176)] = Wpk[i];
  {
    const unsigned int* Ts = (const unsigned int*)Tab;
    unsigned int* Td = (unsigned int*)tab;
    for (int i = tid; i < 32 * 130; i += 256) Td[i] = Ts[i];
  }
  for (int i = tid; i < 26 * 32; i += 256) {
    int rr = i >> 5, cc = i & 31;
    unsigned int v = 0;
    if (cc < 26) {
      int py = y0 + rr - 5, px = x0 + cc - 5;
      if (py >= 0 && py < HP && px >= 0 && px < HP) {
        int uy = py - PADN; uy = uy < 0 ? -uy : (uy >= HH ? 2 * (HH - 1) - uy : uy);
        int ux = px - PADN; ux = ux < 0 ? -ux : (ux >= WW ? 2 * (WW - 1) - ux : ux);
        const float* up = &u_t[((n * HH + uy) * WW + ux) * 2];
        v = pack_bf(up[0], up[1]);
      }
    }
    tIn[i] = v;
  }
  __syncthreads();
  int lane = tid & 63, wave = tid >> 6;
  int m16 = lane & 15, kq = lane >> 4;
  const short* lWs = (const short*)lW;
  f32x4 acc[4][2] = {};
  for (int ky = 0; ky < 11; ky++) {
    bf16x8 af0 = *(const bf16x8*)&lWs[m16 * 360 + ky * 32 + kq * 8];
    bf16x8 af1 = *(const bf16x8*)&lWs[(m16 + 16) * 360 + ky * 32 + kq * 8];
    #pragma unroll
    for (int nt = 0; nt < 4; nt++) {
      int rr = wave * 4 + nt + ky;
      int c0 = rr * 32 + m16 + kq * 4;
      union { unsigned int u[4]; bf16x8 v; } bu;
      bu.u[0] = tIn[c0]; bu.u[1] = tIn[c0 + 1];
      bu.u[2] = tIn[c0 + 2]; bu.u[3] = tIn[c0 + 3];
      acc[nt][0] = MFMA16(af0, bu.v, acc[nt][0], 0, 0, 0);
      acc[nt][1] = MFMA16(af1, bu.v, acc[nt][1], 0, 0, 0);
    }
  }
  // RBF via table lookup + lerp. C layout: col=lane&15 (x), row=kq*4+r (o)
  const float tscale = (float)TABN / 4.0f;    // 64 per unit v
  #pragma unroll
  for (int nt = 0; nt < 4; nt++) {
    int Y = y0 + wave * 4 + nt;
    int X = x0 + m16;
    if (Y >= HP || X >= HP) continue;
    #pragma unroll
    for (int mt = 0; mt < 2; mt++) {
      u16x4 pk;
      #pragma unroll
      for (int r = 0; r < 4; r++) {
        float v = acc[nt][mt][r];
        int o = mt * 16 + kq * 4 + r;
        float t = (v + 2.0f) * tscale;
        t = fminf(fmaxf(t, 0.0f), 255.999f);
        int i0 = (int)t;
        float fr = t - (float)i0;
        float a = b2f(tab[o * 260 + i0]);
        float bv = b2f(tab[o * 260 + i0 + 1]);
        pk[r] = f2b(a + (bv - a) * fr);
      }
      *(u16x4*)&fukT[(((size_t)n * HP + Y) * HP + X) * 32 + mt * 16 + kq * 4] = pk;
    }
  }
}

// ---------------- K3: transposed conv via MFMA -----------------------------
__global__ __launch_bounds__(256) void k_convT_mfma(
    const unsigned short* __restrict__ fukT, const unsigned short* __restrict__ Wt,
    float* __restrict__ Ru) {
  __shared__ unsigned short rowBuf[42 * 32];
  __shared__ float accS[16 * 67];
  int n = blockIdx.z;
  int y0 = blockIdx.y * 16, x0 = blockIdx.x * 32;
  int tid = threadIdx.x;
  int lane = tid & 63, wave = tid >> 6;
  int ch = wave >> 1, xh = wave & 1;
  int m16 = lane & 15, kq = lane >> 4;
  bf16x8 afr[11];
  #pragma unroll
  for (int kx = 0; kx < 11; kx++)
    afr[kx] = *(const bf16x8*)&Wt[((ch * 11 + kx) * 16 + m16) * 32 + kq * 8];
  for (int i = tid; i < 16 * 67; i += 256) accS[i] = 0.f;
  int xl = xh * 16 + m16;
  for (int t = 0; t < 26; t++) {
    int r = y0 + 6 + t;
    __syncthreads();
    {
      const unsigned int* src = (const unsigned int*)&fukT[(((size_t)n * HP + r) * HP + x0 + 6) * 32];
      unsigned int* dst = (unsigned int*)rowBuf;
      for (int i = tid; i < 42 * 16; i += 256) dst[i] = src[i];
    }
    __syncthreads();
    f32x4 dacc = {};
    #pragma unroll
    for (int kx = 0; kx < 11; kx++) {
      bf16x8 bfrag = *(const bf16x8*)&rowBuf[(xl + 10 - kx) * 32 + kq * 8];
      dacc = MFMA16(afr[kx], bfrag, dacc, 0, 0, 0);
    }
    #pragma unroll
    for (int rg = 0; rg < 4; rg++) {
      int ky = kq * 4 + rg;
      int y = t + ky - 10;
      if (ky <= 10 && y >= 0 && y < 16)
        accS[y * 67 + xl * 2 + ch] += dacc[rg];
    }
  }
  __syncthreads();
  int chO = tid & 1, xO = (tid >> 1) & 31, yb = tid >> 6;
  #pragma unroll
  for (int q = 0; q < 4; q++) {
    int y = yb + q * 4;
    Ru[(((size_t)n * HH + y0 + y) * WW + x0 + xO) * 2 + chO] = accS[y * 67 + xO * 2 + chO];
  }
}

// ---------------- K4: X0T = (u * coil_sens)^T, PACKED fragments ------------
__global__ __launch_bounds__(256) void k_umulT(const float* __restrict__ u_t,
                                               const float* __restrict__ cs,
                                               unsigned int* __restrict__ X0T) {
  __shared__ unsigned int t[32 * 33];
  int bc = blockIdx.x;                 // 0..99 tile
  int b = blockIdx.y;                  // 0..59 (n*CC+c)
  int n = b / CC;
  int ty = (bc / 10) * 32, tx = (bc % 10) * 32;
  int r = threadIdx.x >> 5, c = threadIdx.x & 31;
  #pragma unroll
  for (int q = 0; q < 4; q++) {
    int y = ty + r + q * 8, x = tx + c;
    const float* up = &u_t[((size_t)n * HW + (size_t)y * WW + x) * 2];
    const float* cp = &cs[((size_t)b * HW + (size_t)y * WW + x) * 2];
    float ur = up[0], ui = up[1], crr = cp[0], cii = cp[1];
    t[(r + q * 8) * 33 + c] = pack_bf(ur * crr - ui * cii, ur * cii + ui * crr);
  }
  __syncthreads();
  #pragma unroll
  for (int q = 0; q < 4; q++) {
    int xx = r + q * 8;                // local x (transposed row)
    int x = tx + xx, y = ty + c;
    X0T[(size_t)b * HW + pk_idx(x, y)] = t[c * 33 + xx];
  }
}

// ---------------- K5: fused double complex GEMM (one FFT2 pass) ------------
// 32-row strips, 4 waves/block (4 col-groups of 80), 600 blocks.
// Register tile per wave: 32 rows (nA=2 frags) x 80 cols (nB=5 frags)
//   -> 20 MFMAs per 5 KB of VMEM (B only); A comes from LDS:
//   stage 1 A = F-strip preloaded once (40 KB); stage 2 A = T park in LDS.
// This fixes the VMEM-return-path bound (was 6 KB per 10 MFMAs -> 9% util).
// MODE 1: P2 = mask .* (F*X0*F - f), written TRANSPOSED-PACKED
// MODE 2: Q = conj(F)*P2*conj(F) = conj(conj(T)*F), T = conj(F)*P2; natural out
template <int MODE>
__global__ __launch_bounds__(256, 2) void k_dcpair(
    const unsigned int* __restrict__ Fpk,   // packed F fragments
    const unsigned int* __restrict__ Bp,    // packed B fragments per batch
    const float* __restrict__ mask, const float* __restrict__ fdat,
    unsigned int* __restrict__ Out) {
  __shared__ unsigned int sMem[10560];      // 42240 B: A-frags / T-park / epi
  int bid = blockIdx.x;
  int wg = (bid & 7) * 75 + (bid >> 3);     // XCD swizzle (600 = 8*75, bijective)
  int b = wg / 10, strip = wg % 10;
  int i0 = strip * 32;
  int tid = threadIdx.x;
  int lane = tid & 63, wc = tid >> 6;       // 4 waves = 4 col groups of 80
  int m16 = lane & 15, kq = lane >> 4;
  int loff = m16 * 16 + kq * 4;             // lane word offset inside fragment
  const unsigned int XA1 = (MODE == 1) ? 0x80000000u : 0u;
  const unsigned int XA2 = (MODE == 1) ? 0u : 0x00008000u;

  const unsigned int* Bb = Bp + (size_t)b * HW + (size_t)(wc * 5) * 5120 + loff;

  // issue first B prefetches early (overlap with A-preload)
  uint4 b0[5], b1[5];
  #pragma unroll
  for (int ct = 0; ct < 5; ct++) {
    b0[ct] = *(const uint4*)&Bb[ct * 5120];
    b1[ct] = *(const uint4*)&Bb[ct * 5120 + 256];
  }
  // ---- preload A strip (2 row-frags x 20 k-frags = 40 KB) into LDS ----
  {
    const uint4* src = (const uint4*)(Fpk + (size_t)strip * 10240);
    #pragma unroll
    for (int q = 0; q < 10; q++)
      *(uint4*)&sMem[q * 1024 + tid * 4] = src[q * 256 + tid];
  }
  __syncthreads();

  // ---- stage 1: T = (A-transform F) * B ----
  f32x4 aR0[5] = {}, aI0[5] = {}, aR1[5] = {}, aI1[5] = {};
  uint4 ac0 = *(const uint4*)&sMem[loff];
  uint4 ac1 = *(const uint4*)&sMem[5120 + loff];
  #pragma unroll
  for (int kc2 = 0; kc2 < 10; kc2++) {
    {  // even step kc = 2*kc2
      const int kc = kc2 * 2;
      uint4 an0 = *(const uint4*)&sMem[(kc + 1) * 256 + loff];
      uint4 an1 = *(const uint4*)&sMem[5120 + (kc + 1) * 256 + loff];
      bf16x8 x10 = xf4(ac0, XA1), x20 = xr4(ac0, XA2);
      bf16x8 x11 = xf4(ac1, XA1), x21 = xr4(ac1, XA2);
      bf16x8 bc[5];
      #pragma unroll
      for (int ct = 0; ct < 5; ct++) bc[ct] = *(const bf16x8*)&b0[ct];
      if (kc + 2 < 20) {
        #pragma unroll
        for (int ct = 0; ct < 5; ct++)
          b0[ct] = *(const uint4*)&Bb[ct * 5120 + (kc + 2) * 256];
      }
      #pragma unroll
      for (int ct = 0; ct < 5; ct++) {
        aR0[ct] = MFMA16(x10, bc[ct], aR0[ct], 0, 0, 0);
        aI0[ct] = MFMA16(x20, bc[ct], aI0[ct], 0, 0, 0);
        aR1[ct] = MFMA16(x11, bc[ct], aR1[ct], 0, 0, 0);
        aI1[ct] = MFMA16(x21, bc[ct], aI1[ct], 0, 0, 0);
      }
      ac0 = an0; ac1 = an1;
    }
    {  // odd step kc = 2*kc2+1
      const int kc = kc2 * 2 + 1;
      uint4 an0, an1;
      if (kc + 1 < 20) {
        an0 = *(const uint4*)&sMem[(kc + 1) * 256 + loff];
        an1 = *(const uint4*)&sMem[5120 + (kc + 1) * 256 + loff];
      }
      bf16x8 x10 = xf4(ac0, XA1), x20 = xr4(ac0, XA2);
      bf16x8 x11 = xf4(ac1, XA1), x21 = xr4(ac1, XA2);
      bf16x8 bc[5];
      #pragma unroll
      for (int ct = 0; ct < 5; ct++) bc[ct] = *(const bf16x8*)&b1[ct];
      if (kc + 2 < 20) {
        #pragma unroll
        for (int ct = 0; ct < 5; ct++)
          b1[ct] = *(const uint4*)&Bb[ct * 5120 + (kc + 2) * 256];
      }
      #pragma unroll
      for (int ct = 0; ct < 5; ct++) {
        aR0[ct] = MFMA16(x10, bc[ct], aR0[ct], 0, 0, 0);
        aI0[ct] = MFMA16(x20, bc[ct], aI0[ct], 0, 0, 0);
        aR1[ct] = MFMA16(x11, bc[ct], aR1[ct], 0, 0, 0);
        aI1[ct] = MFMA16(x21, bc[ct], aI1[ct], 0, 0, 0);
      }
      if (kc + 1 < 20) { ac0 = an0; ac1 = an1; }
    }
  }

  // ---- park T in LDS, packed-fragment layout (conj for MODE 2) ----
  __syncthreads();   // all waves done reading A-lds before overwrite
  #pragma unroll
  for (int ct = 0; ct < 5; ct++)
    #pragma unroll
    for (int r = 0; r < 4; r++) {
      unsigned int v0 = pack_bf(aR0[ct][r], aI0[ct][r]);
      unsigned int v1 = pack_bf(aR1[ct][r], aI1[ct][r]);
      if (MODE == 2) { v0 ^= 0x80000000u; v1 ^= 0x80000000u; }
      int w = (kq * 4 + r) * 16 + m16;
      sMem[(wc * 5 + ct) * 256 + w] = v0;
      sMem[(20 + wc * 5 + ct) * 256 + w] = v1;
    }
  __syncthreads();

  // ---- stage 2: Out = T * F (B = raw F for both modes) ----
  f32x4 cR0[5] = {}, cI0[5] = {}, cR1[5] = {}, cI1[5] = {};
  const unsigned int* Fb = Fpk + (size_t)(wc * 5) * 5120 + loff;
  uint4 f0[5], f1[5];
  #pragma unroll
  for (int ct = 0; ct < 5; ct++) {
    f0[ct] = *(const uint4*)&Fb[ct * 5120];
    f1[ct] = *(const uint4*)&Fb[ct * 5120 + 256];
  }
  uint4 tc0 = *(const uint4*)&sMem[loff];
  uint4 tc1 = *(const uint4*)&sMem[5120 + loff];
  #pragma unroll
  for (int kc2 = 0; kc2 < 10; kc2++) {
    {  // even step kc = 2*kc2
      const int kc = kc2 * 2;
      uint4 tn0 = *(const uint4*)&sMem[(kc + 1) * 256 + loff];
      uint4 tn1 = *(const uint4*)&sMem[5120 + (kc + 1) * 256 + loff];
      bf16x8 x10 = xf4(tc0, 0x80000000u), x20 = xr4(tc0, 0u);
      bf16x8 x11 = xf4(tc1, 0x80000000u), x21 = xr4(tc1, 0u);
      bf16x8 bc[5];
      #pragma unroll
      for (int ct = 0; ct < 5; ct++) bc[ct] = *(const bf16x8*)&f0[ct];
      if (kc + 2 < 20) {
        #pragma unroll
        for (int ct = 0; ct < 5; ct++)
          f0[ct] = *(const uint4*)&Fb[ct * 5120 + (kc + 2) * 256];
      }
      #pragma unroll
      for (int ct = 0; ct < 5; ct++) {
        cR0[ct] = MFMA16(x10, bc[ct], cR0[ct], 0, 0, 0);
        cI0[ct] = MFMA16(x20, bc[ct], cI0[ct], 0, 0, 0);
        cR1[ct] = MFMA16(x11, bc[ct], cR1[ct], 0, 0, 0);
        cI1[ct] = MFMA16(x21, bc[ct], cI1[ct], 0, 0, 0);
      }
      tc0 = tn0; tc1 = tn1;
    }
    {  // odd step kc = 2*kc2+1
      const int kc = kc2 * 2 + 1;
      uint4 tn0, tn1;
      if (kc + 1 < 20) {
        tn0 = *(const uint4*)&sMem[(kc + 1) * 256 + loff];
        tn1 = *(const uint4*)&sMem[5120 + (kc + 1) * 256 + loff];
      }
      bf16x8 x10 = xf4(tc0, 0x80000000u), x20 = xr4(tc0, 0u);
      bf16x8 x11 = xf4(tc1, 0x80000000u), x21 = xr4(tc1, 0u);
      bf16x8 bc[5];
      #pragma unroll
      for (int ct = 0; ct < 5; ct++) bc[ct] = *(const bf16x8*)&f1[ct];
      if (kc + 2 < 20) {
        #pragma unroll
        for (int ct = 0; ct < 5; ct++)
          f1[ct] = *(const uint4*)&Fb[ct * 5120 + (kc + 2) * 256];
      }
      #pragma unroll
      for (int ct = 0; ct < 5; ct++) {
        cR0[ct] = MFMA16(x10, bc[ct], cR0[ct], 0, 0, 0);
        cI0[ct] = MFMA16(x20, bc[ct], cI0[ct], 0, 0, 0);
        cR1[ct] = MFMA16(x11, bc[ct], cR1[ct], 0, 0, 0);
        cI1[ct] = MFMA16(x21, bc[ct], cI1[ct], 0, 0, 0);
      }
      if (kc + 1 < 20) { tc0 = tn0; tc1 = tn1; }
    }
  }

  // ---- epilogue ----
  if constexpr (MODE == 1) {
    __syncthreads();   // all waves done reading T before overwrite
    int n = b / CC;
    #pragma unroll
    for (int ct = 0; ct < 5; ct++)
      #pragma unroll
      for (int r = 0; r < 4; r++) {
        int col = wc * 80 + ct * 16 + m16;
        {
          int lrow = kq * 4 + r, row = i0 + lrow;
          float m = mask[n * HW + row * WW + col];
          size_t fi = ((size_t)b * HW + (size_t)row * WW + col) * 2;
          float vr = m * (cR0[ct][r] - fdat[fi]);
          float vi = m * (cI0[ct][r] - fdat[fi + 1]);
          sMem[col * 33 + lrow] = pack_bf(vr, vi);
        }
        {
          int lrow = 16 + kq * 4 + r, row = i0 + lrow;
          float m = mask[n * HW + row * WW + col];
          size_t fi = ((size_t)b * HW + (size_t)row * WW + col) * 2;
          float vr = m * (cR1[ct][r] - fdat[fi]);
          float vi = m * (cI1[ct][r] - fdat[fi + 1]);
          sMem[col * 33 + lrow] = pack_bf(vr, vi);
        }
      }
    __syncthreads();
    for (int i2 = tid; i2 < 320 * 32; i2 += 256) {
      int x = i2 >> 5, yy = i2 & 31;
      Out[(size_t)b * HW + pk_idx(x, i0 + yy)] = sMem[x * 33 + yy];
    }
  } else {
    // natural layout for k_coilsum; conjugate on store
    #pragma unroll
    for (int ct = 0; ct < 5; ct++)
      #pragma unroll
      for (int r = 0; r < 4; r++) {
        int col = wc * 80 + ct * 16 + m16;
        int row0 = i0 + kq * 4 + r;
        int row1 = i0 + 16 + kq * 4 + r;
        Out[(size_t)b * HW + (size_t)row0 * WW + col] =
            pack_bf(cR0[ct][r], cI0[ct][r]) ^ 0x80000000u;
        Out[(size_t)b * HW + (size_t)row1 * WW + col] =
            pack_bf(cR1[ct][r], cI1[ct][r]) ^ 0x80000000u;
      }
  }
}

// ---------------- K6: coil-combine with conj(sens), bf16-pair input --------
__global__ void k_coilsum(const unsigned int* __restrict__ Z, const float* __restrict__ cs,
                          float* __restrict__ At) {
  int idx = blockIdx.x * blockDim.x + threadIdx.x;
  if (idx >= NN * HW) return;
  int n = idx / HW, hw = idx % HW;
  float ar = 0.f, ai = 0.f;
  for (int c = 0; c < CC; c++) {
    size_t zi = (size_t)(n * CC + c) * HW + hw;
    unsigned int p = Z[zi];
    float zr = b2f((unsigned short)(p & 0xffff));
    float zim = b2f((unsigned short)(p >> 16));
    float crr = cs[zi * 2], cii = cs[zi * 2 + 1];
    ar += zr * crr + zim * cii;
    ai += zim * crr - zr * cii;
  }
  At[idx * 2] = ar;
  At[idx * 2 + 1] = ai;
}

// ---------------- K7: out = u - Ru/FF - lamb*At ----------------------------
__global__ void k_final(const float* __restrict__ u_t, const float* __restrict__ Ru,
                        const float* __restrict__ At, const float* __restrict__ lamb,
                        float* __restrict__ out) {
  int idx = blockIdx.x * blockDim.x + threadIdx.x;
  if (idx >= NN * HW * 2) return;
  out[idx] = u_t[idx] - Ru[idx] * (1.0f / (float)FF) - lamb[0] * At[idx];
}

extern "C" void kernel_launch(void* const* d_in, const int* in_sizes, int n_in,
                              void* d_out, int out_size, void* d_ws, size_t ws_size,
                              hipStream_t stream) {
  const float* u_t   = (const float*)d_in[0];
  const float* fdat  = (const float*)d_in[1];
  const float* cs    = (const float*)d_in[2];
  const float* mask  = (const float*)d_in[3];
  const float* ck    = (const float*)d_in[4];
  const float* w     = (const float*)d_in[5];
  const float* mu    = (const float*)d_in[6];
  const float* sigma = (const float*)d_in[7];
  const float* lamb  = (const float*)d_in[8];
  float* out = (float*)d_out;

  // ws layout (u32 words):
  //  Fpk @0          102400  (fragment-packed DFT matrix)
  //  Wpk @102400     5760
  //  Wt  @108160     5632
  //  Tab @113792     4160
  //  At  @117952     819200
  //  Ru  @937152     819200
  //  big @1756352    12288000
  //   conv phase: fukT [7485696 w]
  //   DC phase:   X0T @big [6144000] ; P2T @big+6144000 [6144000] ; Q @big
  unsigned int* wsw = (unsigned int*)d_ws;
  unsigned int* Fpk = wsw;
  unsigned int* Wpk = wsw + 102400;
  unsigned short* Wt = (unsigned short*)(wsw + 108160);
  unsigned short* Tab = (unsigned short*)(wsw + 113792);
  float* At = (float*)(wsw + 117952);
  float* Ru = (float*)(wsw + 937152);
  unsigned int* big = wsw + 1756352;
  unsigned short* fukT = (unsigned short*)big;
  unsigned int* X0T = big;
  unsigned int* P2T = big + 6144000;
  unsigned int* Q = big;

  k_dft<<<(HW + 255) / 256, 256, 0, stream>>>(Fpk);
  k_prep<<<(32 * 176 + 255) / 256, 256, 0, stream>>>(ck, Wpk);
  k_prep2<<<(2 * 11 * 16 * 32 + 255) / 256, 256, 0, stream>>>(ck, Wt);
  k_rbftab<<<32, 320, 0, stream>>>(w, mu, sigma, Tab);
  k_conv_rbf_mfma<<<dim3(22, 22, NN), 256, 0, stream>>>(u_t, Wpk, Tab, fukT);
  k_convT_mfma<<<dim3(10, 20, NN), 256, 0, stream>>>(fukT, Wt, Ru);
  k_umulT<<<dim3(100, 60), 256, 0, stream>>>(u_t, cs, X0T);
  k_dcpair<1><<<600, 256, 0, stream>>>(Fpk, X0T, mask, fdat, P2T);
  k_dcpair<2><<<600, 256, 0, stream>>>(Fpk, P2T, nullptr, nullptr, Q);
  k_coilsum<<<(NN * HW + 255) / 256, 256, 0, stream>>>(Q, cs, At);
  k_final<<<(NN * HW * 2 + 255) / 256, 256, 0, stream>>>(u_t, Ru, At, lamb, out);
}

// Round 5
// 380.354 us; speedup vs baseline: 1.2053x; 1.0221x over previous
//
#include <hip/hip_runtime.h>
#include <hip/hip_bf16.h>
#include <math.h>

#define NN 4
#define CC 15
#define HH 320
#define WW 320
#define HW (HH*WW)          // 102400
#define FF 32
#define KS 11
#define PADN 11
#define CPAD 5
#define HP 342
#define NK 31
#define NCB (NN*CC)
#define TABN 256            // intervals; 257 entries, stride 260

typedef short bf16x8 __attribute__((ext_vector_type(8)));
typedef float f32x4 __attribute__((ext_vector_type(4)));
typedef unsigned short u16x4 __attribute__((ext_vector_type(4)));

#define MFMA16 __builtin_amdgcn_mfma_f32_16x16x32_bf16

__device__ __forceinline__ unsigned int pack_bf(float r, float i) {
  __hip_bfloat16 hr = __float2bfloat16(r), hi = __float2bfloat16(i);
  unsigned short ur = *(unsigned short*)&hr, ui = *(unsigned short*)&hi;
  return (unsigned int)ur | ((unsigned int)ui << 16);
}
__device__ __forceinline__ unsigned short f2b(float x) {
  __hip_bfloat16 h = __float2bfloat16(x);
  return *(unsigned short*)&h;
}
__device__ __forceinline__ float b2f(unsigned short u) {
  __hip_bfloat16 h = *(__hip_bfloat16*)&u;
  return __bfloat162float(h);
}
__device__ __forceinline__ unsigned int rot16(unsigned int x) {
  return (x >> 16) | (x << 16);
}
// complex-pair fragment transforms
__device__ __forceinline__ bf16x8 xf4(uint4 p, unsigned int x) {
  union { unsigned int u[4]; bf16x8 v; } t;
  t.u[0] = p.x ^ x; t.u[1] = p.y ^ x; t.u[2] = p.z ^ x; t.u[3] = p.w ^ x;
  return t.v;
}
__device__ __forceinline__ bf16x8 xr4(uint4 p, unsigned int x) {
  union { unsigned int u[4]; bf16x8 v; } t;
  t.u[0] = rot16(p.x) ^ x; t.u[1] = rot16(p.y) ^ x;
  t.u[2] = rot16(p.z) ^ x; t.u[3] = rot16(p.w) ^ x;
  return t.v;
}
// chunk-granular (16B) XOR swizzle inside a 256-word fragment; involution.
// Spreads the wave's ds_read_b128 pattern from 8-way to free 2-way conflicts.
__device__ __forceinline__ int swzw(int w) {
  int c = w >> 2;
  c ^= (c >> 3) & 7;
  return (c << 2) | (w & 3);
}
// fragment-packed index (swizzled): [row][col] -> frag(row>>4, col>>4), word
// swzw((row&15)*16 + (col&15)). All packed buffers use this layout.
__device__ __forceinline__ size_t pk_idx(int row, int col) {
  return (size_t)((row >> 4) * 20 + (col >> 4)) * 256 + swzw((row & 15) * 16 + (col & 15));
}

// ---------------- K0: centered orthonormal DFT matrix, bf16 pairs, PACKED --
__global__ void k_dft(unsigned int* __restrict__ Fpk) {
  int idx = blockIdx.x * blockDim.x + threadIdx.x;
  if (idx >= HW) return;
  int k = idx / WW, n = idx % WW;
  int prod = (k - 160) * (n - 160);
  int r = prod % 320; if (r < 0) r += 320;
  float ang = -6.283185307179586f * (float)r / 320.0f;
  const float s = 0.05590169943749474f; // 1/sqrt(320)
  Fpk[pk_idx(k, n)] = pack_bf(cosf(ang) * s, sinf(ang) * s);
}

// ---------------- K0b: prepack conv weights (forward, A-operand) -----------
__global__ void k_prep(const float* __restrict__ ck, unsigned int* __restrict__ Wpk) {
  int idx = blockIdx.x * blockDim.x + threadIdx.x;
  if (idx >= 32 * 176) return;
  int o = idx / 176, kw = idx % 176;
  int ky = kw / 16, kx = kw % 16;
  unsigned int v = 0;
  if (kx <= 10) {
    const float* p = &ck[(o * 121 + ky * 11 + kx) * 2];
    v = pack_bf(p[0], p[1]);
  }
  Wpk[idx] = v;
}

// ---------------- K0c: prepack adjoint weights Wt[ch][kx][ky16][o32] -------
__global__ void k_prep2(const float* __restrict__ ck, unsigned short* __restrict__ Wt) {
  int idx = blockIdx.x * blockDim.x + threadIdx.x;
  if (idx >= 2 * 11 * 16 * 32) return;
  int o = idx & 31;
  int ky = (idx >> 5) & 15;
  int rest = idx >> 9;
  int kx = rest % 11, ch = rest / 11;
  unsigned short v = 0;
  if (ky <= 10) v = f2b(ck[(o * 121 + ky * 11 + kx) * 2 + ch]);
  Wt[idx] = v;
}

// ---------------- K0d: RBF lookup table, bf16, [-2,2], 257 entries ---------
__global__ void k_rbftab(const float* __restrict__ w, const float* __restrict__ mu,
                         const float* __restrict__ sigma, unsigned short* __restrict__ Tab) {
  int o = blockIdx.x;
  int e = threadIdx.x;
  if (e >= TABN + 1) return;
  float v = -2.0f + (float)e * (4.0f / (float)TABN);
  float sg = sigma[0];
  float nInv = -1.0f / (2.0f * sg * sg);
  float acc = 0.f;
  for (int i = 0; i < NK; i++) {
    float d = v - mu[i];
    acc += w[o * NK + i] * __expf(d * d * nInv);
  }
  Tab[o * 260 + e] = f2b(acc);
}

// ---------------- K2: conv(11x11) + RBF(table) via MFMA implicit GEMM ------
__global__ __launch_bounds__(256) void k_conv_rbf_mfma(
    const float* __restrict__ u_t, const unsigned int* __restrict__ Wpk,
    const unsigned short* __restrict__ Tab, unsigned short* __restrict__ fukT) {
  __shared__ unsigned int lW[32 * 180];       // 23040 B
  __shared__ unsigned int tIn[26 * 32];       // 3328 B
  __shared__ unsigned short tab[32 * 260];    // 16640 B
  int n = blockIdx.z;
  int y0 = blockIdx.y * 16, x0 = blockIdx.x * 16;
  int tid = threadIdx.x;
  for (int i = tid; i < 32 * 176; i += 256)
    lW[(i / 176) * 180 + (i % 176)] = Wpk[i];
  {
    const unsigned int* Ts = (const unsigned int*)Tab;
    unsigned int* Td = (unsigned int*)tab;
    for (int i = tid; i < 32 * 130; i += 256) Td[i] = Ts[i];
  }
  for (int i = tid; i < 26 * 32; i += 256) {
    int rr = i >> 5, cc = i & 31;
    unsigned int v = 0;
    if (cc < 26) {
      int py = y0 + rr - 5, px = x0 + cc - 5;
      if (py >= 0 && py < HP && px >= 0 && px < HP) {
        int uy = py - PADN; uy = uy < 0 ? -uy : (uy >= HH ? 2 * (HH - 1) - uy : uy);
        int ux = px - PADN; ux = ux < 0 ? -ux : (ux >= WW ? 2 * (WW - 1) - ux : ux);
        const float* up = &u_t[((n * HH + uy) * WW + ux) * 2];
        v = pack_bf(up[0], up[1]);
      }
    }
    tIn[i] = v;
  }
  __syncthreads();
  int lane = tid & 63, wave = tid >> 6;
  int m16 = lane & 15, kq = lane >> 4;
  const short* lWs = (const short*)lW;
  f32x4 acc[4][2] = {};
  for (int ky = 0; ky < 11; ky++) {
    bf16x8 af0 = *(const bf16x8*)&lWs[m16 * 360 + ky * 32 + kq * 8];
    bf16x8 af1 = *(const bf16x8*)&lWs[(m16 + 16) * 360 + ky * 32 + kq * 8];
    #pragma unroll
    for (int nt = 0; nt < 4; nt++) {
      int rr = wave * 4 + nt + ky;
      int c0 = rr * 32 + m16 + kq * 4;
      union { unsigned int u[4]; bf16x8 v; } bu;
      bu.u[0] = tIn[c0]; bu.u[1] = tIn[c0 + 1];
      bu.u[2] = tIn[c0 + 2]; bu.u[3] = tIn[c0 + 3];
      acc[nt][0] = MFMA16(af0, bu.v, acc[nt][0], 0, 0, 0);
      acc[nt][1] = MFMA16(af1, bu.v, acc[nt][1], 0, 0, 0);
    }
  }
  const float tscale = (float)TABN / 4.0f;    // 64 per unit v
  #pragma unroll
  for (int nt = 0; nt < 4; nt++) {
    int Y = y0 + wave * 4 + nt;
    int X = x0 + m16;
    if (Y >= HP || X >= HP) continue;
    #pragma unroll
    for (int mt = 0; mt < 2; mt++) {
      u16x4 pk;
      #pragma unroll
      for (int r = 0; r < 4; r++) {
        float v = acc[nt][mt][r];
        int o = mt * 16 + kq * 4 + r;
        float t = (v + 2.0f) * tscale;
        t = fminf(fmaxf(t, 0.0f), 255.999f);
        int i0 = (int)t;
        float fr = t - (float)i0;
        float a = b2f(tab[o * 260 + i0]);
        float bv = b2f(tab[o * 260 + i0 + 1]);
        pk[r] = f2b(a + (bv - a) * fr);
      }
      *(u16x4*)&fukT[(((size_t)n * HP + Y) * HP + X) * 32 + mt * 16 + kq * 4] = pk;
    }
  }
}

// ---------------- K3: transposed conv via MFMA -----------------------------
__global__ __launch_bounds__(256) void k_convT_mfma(
    const unsigned short* __restrict__ fukT, const unsigned short* __restrict__ Wt,
    float* __restrict__ Ru) {
  __shared__ unsigned short rowBuf[42 * 32];
  __shared__ float accS[16 * 67];
  int n = blockIdx.z;
  int y0 = blockIdx.y * 16, x0 = blockIdx.x * 32;
  int tid = threadIdx.x;
  int lane = tid & 63, wave = tid >> 6;
  int ch = wave >> 1, xh = wave & 1;
  int m16 = lane & 15, kq = lane >> 4;
  bf16x8 afr[11];
  #pragma unroll
  for (int kx = 0; kx < 11; kx++)
    afr[kx] = *(const bf16x8*)&Wt[((ch * 11 + kx) * 16 + m16) * 32 + kq * 8];
  for (int i = tid; i < 16 * 67; i += 256) accS[i] = 0.f;
  int xl = xh * 16 + m16;
  for (int t = 0; t < 26; t++) {
    int r = y0 + 6 + t;
    __syncthreads();
    {
      const unsigned int* src = (const unsigned int*)&fukT[(((size_t)n * HP + r) * HP + x0 + 6) * 32];
      unsigned int* dst = (unsigned int*)rowBuf;
      for (int i = tid; i < 42 * 16; i += 256) dst[i] = src[i];
    }
    __syncthreads();
    f32x4 dacc = {};
    #pragma unroll
    for (int kx = 0; kx < 11; kx++) {
      bf16x8 bfrag = *(const bf16x8*)&rowBuf[(xl + 10 - kx) * 32 + kq * 8];
      dacc = MFMA16(afr[kx], bfrag, dacc, 0, 0, 0);
    }
    #pragma unroll
    for (int rg = 0; rg < 4; rg++) {
      int ky = kq * 4 + rg;
      int y = t + ky - 10;
      if (ky <= 10 && y >= 0 && y < 16)
        accS[y * 67 + xl * 2 + ch] += dacc[rg];
    }
  }
  __syncthreads();
  int chO = tid & 1, xO = (tid >> 1) & 31, yb = tid >> 6;
  #pragma unroll
  for (int q = 0; q < 4; q++) {
    int y = yb + q * 4;
    Ru[(((size_t)n * HH + y0 + y) * WW + x0 + xO) * 2 + chO] = accS[y * 67 + xO * 2 + chO];
  }
}

// ---------------- K4: X0T = (u * coil_sens)^T, PACKED (swizzled) fragments -
__global__ __launch_bounds__(256) void k_umulT(const float* __restrict__ u_t,
                                               const float* __restrict__ cs,
                                               unsigned int* __restrict__ X0T) {
  __shared__ unsigned int t[32 * 33];
  int bc = blockIdx.x;                 // 0..99 tile
  int b = blockIdx.y;                  // 0..59 (n*CC+c)
  int n = b / CC;
  int ty = (bc / 10) * 32, tx = (bc % 10) * 32;
  int r = threadIdx.x >> 5, c = threadIdx.x & 31;
  #pragma unroll
  for (int q = 0; q < 4; q++) {
    int y = ty + r + q * 8, x = tx + c;
    const float* up = &u_t[((size_t)n * HW + (size_t)y * WW + x) * 2];
    const float* cp = &cs[((size_t)b * HW + (size_t)y * WW + x) * 2];
    float ur = up[0], ui = up[1], crr = cp[0], cii = cp[1];
    t[(r + q * 8) * 33 + c] = pack_bf(ur * crr - ui * cii, ur * cii + ui * crr);
  }
  __syncthreads();
  #pragma unroll
  for (int q = 0; q < 4; q++) {
    int xx = r + q * 8;                // local x (transposed row)
    int x = tx + xx, y = ty + c;
    X0T[(size_t)b * HW + pk_idx(x, y)] = t[c * 33 + xx];
  }
}

// ---------------- K5: fused double complex GEMM via async LDS-DMA ----------
// 32-row strips, 4 waves (4 col-groups of 80), 600 blocks, wave tile (2,5).
// All GEMM operand streams go global->LDS via __builtin_amdgcn_global_load_lds
// (quad-buffered ring, 2-row lookahead, counted vmcnt, per-wave-private frags
// => barrier-free K-loops). Fragment layout is chunk-XOR-swizzled (swzw) for
// 2-way LDS reads. A-strip / T-park share sA. Mode-1 output is stored
// directly from registers in packed-transposed layout (C-frag == one uint4).
// MODE 1: P2 = mask .* (F*X0*F - f)  (TRANSPOSED-PACKED out)
// MODE 2: Q = conj(F)*P2*conj(F) = conj(conj(T)*F)  (natural out)
#define BUF4(i) ((i) == 0 ? sB0 : ((i) == 1 ? sB1 : ((i) == 2 ? sB2 : sB3)))

template <int MODE>
__global__ __launch_bounds__(256, 2) void k_dcpair(
    const unsigned int* __restrict__ Fpk,   // packed F fragments (swizzled)
    const unsigned int* __restrict__ Bp,    // packed B fragments per batch
    const float* __restrict__ mask, const float* __restrict__ fdat,
    unsigned int* __restrict__ Out) {
  __shared__ unsigned int sA[10240];                    // A-strip / T-park (40KB)
  __shared__ unsigned int sB0[5120], sB1[5120], sB2[5120], sB3[5120]; // ring 80KB
  int bid = blockIdx.x;
  int wg = (bid & 7) * 75 + (bid >> 3);     // XCD swizzle (600 = 8*75, bijective)
  int b = wg / 10, strip = wg % 10;
  int i0 = strip * 32;
  int tid = threadIdx.x;
  int lane = tid & 63, wc = tid >> 6;       // 4 waves = 4 col groups of 80
  int m16 = lane & 15, kq = lane >> 4;
  int loff = m16 * 16 + kq * 4;             // logical lane word offset in frag
  int loffS = swzw(loff);                   // physical (swizzled) offset
  const unsigned int XA1 = (MODE == 1) ? 0x80000000u : 0u;
  const unsigned int XA2 = (MODE == 1) ? 0u : 0x00008000u;

  const unsigned int* Astrip = Fpk + (size_t)strip * 10240;
  const unsigned int* Bb = Bp + (size_t)b * HW + (size_t)(wc * 5) * 5120;
  const unsigned int* Fb = Fpk + (size_t)(wc * 5) * 5120;

  // ---- prologue: DMA A strip (10 frags/wave) + B rows 0,1 ----
  #pragma unroll
  for (int f = 0; f < 10; f++)
    __builtin_amdgcn_global_load_lds(Astrip + (wc * 10 + f) * 256 + lane * 4,
                                     &sA[(wc * 10 + f) * 256], 16, 0, 0);
  #pragma unroll
  for (int ct = 0; ct < 5; ct++)
    __builtin_amdgcn_global_load_lds(Bb + ct * 5120 + lane * 4,
                                     &sB0[(wc * 5 + ct) * 256], 16, 0, 0);
  #pragma unroll
  for (int ct = 0; ct < 5; ct++)
    __builtin_amdgcn_global_load_lds(Bb + ct * 5120 + 256 + lane * 4,
                                     &sB1[(wc * 5 + ct) * 256], 16, 0, 0);
  __syncthreads();   // drains vmcnt(0): A + rows 0,1 landed; A visible to all

  // ---- stage 1: T = (A-transform F) * B, barrier-free ----
  f32x4 aR0[5] = {}, aI0[5] = {}, aR1[5] = {}, aI1[5] = {};
  #pragma unroll
  for (int kf = 0; kf < 20; kf++) {
    const unsigned int* rdb = BUF4(kf & 3);
    if (kf < 18) {
      unsigned int* stb = BUF4((kf + 2) & 3);
      #pragma unroll
      for (int ct = 0; ct < 5; ct++)
        __builtin_amdgcn_global_load_lds(Bb + ct * 5120 + (kf + 2) * 256 + lane * 4,
                                         &stb[(wc * 5 + ct) * 256], 16, 0, 0);
      asm volatile("s_waitcnt vmcnt(10)" ::: "memory");
    } else if (kf == 18) {
      asm volatile("s_waitcnt vmcnt(5)" ::: "memory");
    } else {
      asm volatile("s_waitcnt vmcnt(0)" ::: "memory");
    }
    uint4 a0 = *(const uint4*)&sA[kf * 256 + loffS];
    uint4 a1 = *(const uint4*)&sA[5120 + kf * 256 + loffS];
    bf16x8 x10 = xf4(a0, XA1), x20 = xr4(a0, XA2);
    bf16x8 x11 = xf4(a1, XA1), x21 = xr4(a1, XA2);
    #pragma unroll
    for (int ct = 0; ct < 5; ct++) {
      uint4 bq = *(const uint4*)&rdb[(wc * 5 + ct) * 256 + loffS];
      bf16x8 bb = *(const bf16x8*)&bq;
      aR0[ct] = MFMA16(x10, bb, aR0[ct], 0, 0, 0);
      aI0[ct] = MFMA16(x20, bb, aI0[ct], 0, 0, 0);
      aR1[ct] = MFMA16(x11, bb, aR1[ct], 0, 0, 0);
      aI1[ct] = MFMA16(x21, bb, aI1[ct], 0, 0, 0);
    }
  }

  // ---- park T in sA (conj for MODE 2); DMA F rows 0,1 ----
  __syncthreads();   // all waves done reading A-strip
  #pragma unroll
  for (int ct = 0; ct < 5; ct++)
    #pragma unroll
    for (int r = 0; r < 4; r++) {
      unsigned int v0 = pack_bf(aR0[ct][r], aI0[ct][r]);
      unsigned int v1 = pack_bf(aR1[ct][r], aI1[ct][r]);
      if (MODE == 2) { v0 ^= 0x80000000u; v1 ^= 0x80000000u; }
      int w = swzw((kq * 4 + r) * 16 + m16);
      sA[(wc * 5 + ct) * 256 + w] = v0;
      sA[(20 + wc * 5 + ct) * 256 + w] = v1;
    }
  #pragma unroll
  for (int ct = 0; ct < 5; ct++)
    __builtin_amdgcn_global_load_lds(Fb + ct * 5120 + lane * 4,
                                     &sB0[(wc * 5 + ct) * 256], 16, 0, 0);
  #pragma unroll
  for (int ct = 0; ct < 5; ct++)
    __builtin_amdgcn_global_load_lds(Fb + ct * 5120 + 256 + lane * 4,
                                     &sB1[(wc * 5 + ct) * 256], 16, 0, 0);
  __syncthreads();   // T visible; F rows 0,1 drained

  // ---- stage 2: Out = T * F, barrier-free (B = raw F for both modes) ----
  f32x4 cR0[5] = {}, cI0[5] = {}, cR1[5] = {}, cI1[5] = {};
  #pragma unroll
  for (int kf = 0; kf < 20; kf++) {
    const unsigned int* rdb = BUF4(kf & 3);
    if (kf < 18) {
      unsigned int* stb = BUF4((kf + 2) & 3);
      #pragma unroll
      for (int ct = 0; ct < 5; ct++)
        __builtin_amdgcn_global_load_lds(Fb + ct * 5120 + (kf + 2) * 256 + lane * 4,
                                         &stb[(wc * 5 + ct) * 256], 16, 0, 0);
      asm volatile("s_waitcnt vmcnt(10)" ::: "memory");
    } else if (kf == 18) {
      asm volatile("s_waitcnt vmcnt(5)" ::: "memory");
    } else {
      asm volatile("s_waitcnt vmcnt(0)" ::: "memory");
    }
    uint4 t0 = *(const uint4*)&sA[kf * 256 + loffS];
    uint4 t1 = *(const uint4*)&sA[5120 + kf * 256 + loffS];
    bf16x8 x10 = xf4(t0, 0x80000000u), x20 = xr4(t0, 0u);
    bf16x8 x11 = xf4(t1, 0x80000000u), x21 = xr4(t1, 0u);
    #pragma unroll
    for (int ct = 0; ct < 5; ct++) {
      uint4 bq = *(const uint4*)&rdb[(wc * 5 + ct) * 256 + loffS];
      bf16x8 bb = *(const bf16x8*)&bq;
      cR0[ct] = MFMA16(x10, bb, cR0[ct], 0, 0, 0);
      cI0[ct] = MFMA16(x20, bb, cI0[ct], 0, 0, 0);
      cR1[ct] = MFMA16(x11, bb, cR1[ct], 0, 0, 0);
      cI1[ct] = MFMA16(x21, bb, cI1[ct], 0, 0, 0);
    }
  }

  // ---- epilogue ----
  if constexpr (MODE == 1) {
    // Direct packed-transposed frag stores: C layout (col=m16, row=kq*4+r)
    // makes each (ct, rowfrag) a single contiguous uint4 at word loff.
    int n = b / CC;
    #pragma unroll
    for (int ct = 0; ct < 5; ct++) {
      int col = wc * 80 + ct * 16 + m16;
      uint4 s0, s1;
      #pragma unroll
      for (int r = 0; r < 4; r++) {
        int row0 = i0 + kq * 4 + r;
        float m0 = mask[n * HW + row0 * WW + col];
        size_t f0i = ((size_t)b * HW + (size_t)row0 * WW + col) * 2;
        ((unsigned int*)&s0)[r] =
            pack_bf(m0 * (cR0[ct][r] - fdat[f0i]), m0 * (cI0[ct][r] - fdat[f0i + 1]));
        int row1 = row0 + 16;
        float m1 = mask[n * HW + row1 * WW + col];
        size_t f1i = ((size_t)b * HW + (size_t)row1 * WW + col) * 2;
        ((unsigned int*)&s1)[r] =
            pack_bf(m1 * (cR1[ct][r] - fdat[f1i]), m1 * (cI1[ct][r] - fdat[f1i + 1]));
      }
      size_t base = (size_t)b * HW + (size_t)((wc * 5 + ct) * 20 + strip * 2) * 256 + loffS;
      *(uint4*)&Out[base] = s0;
      *(uint4*)&Out[base + 256] = s1;
    }
  } else {
    // natural layout for k_coilsum; conjugate on store
    #pragma unroll
    for (int ct = 0; ct < 5; ct++)
      #pragma unroll
      for (int r = 0; r < 4; r++) {
        int col = wc * 80 + ct * 16 + m16;
        int row0 = i0 + kq * 4 + r;
        int row1 = i0 + 16 + kq * 4 + r;
        Out[(size_t)b * HW + (size_t)row0 * WW + col] =
            pack_bf(cR0[ct][r], cI0[ct][r]) ^ 0x80000000u;
        Out[(size_t)b * HW + (size_t)row1 * WW + col] =
            pack_bf(cR1[ct][r], cI1[ct][r]) ^ 0x80000000u;
      }
  }
}

// ---------------- K6: coil-combine with conj(sens), bf16-pair input --------
__global__ void k_coilsum(const unsigned int* __restrict__ Z, const float* __restrict__ cs,
                          float* __restrict__ At) {
  int idx = blockIdx.x * blockDim.x + threadIdx.x;
  if (idx >= NN * HW) return;
  int n = idx / HW, hw = idx % HW;
  float ar = 0.f, ai = 0.f;
  for (int c = 0; c < CC; c++) {
    size_t zi = (size_t)(n * CC + c) * HW + hw;
    unsigned int p = Z[zi];
    float zr = b2f((unsigned short)(p & 0xffff));
    float zim = b2f((unsigned short)(p >> 16));
    float crr = cs[zi * 2], cii = cs[zi * 2 + 1];
    ar += zr * crr + zim * cii;
    ai += zim * crr - zr * cii;
  }
  At[idx * 2] = ar;
  At[idx * 2 + 1] = ai;
}

// ---------------- K7: out = u - Ru/FF - lamb*At ----------------------------
__global__ void k_final(const float* __restrict__ u_t, const float* __restrict__ Ru,
                        const float* __restrict__ At, const float* __restrict__ lamb,
                        float* __restrict__ out) {
  int idx = blockIdx.x * blockDim.x + threadIdx.x;
  if (idx >= NN * HW * 2) return;
  out[idx] = u_t[idx] - Ru[idx] * (1.0f / (float)FF) - lamb[0] * At[idx];
}

extern "C" void kernel_launch(void* const* d_in, const int* in_sizes, int n_in,
                              void* d_out, int out_size, void* d_ws, size_t ws_size,
                              hipStream_t stream) {
  const float* u_t   = (const float*)d_in[0];
  const float* fdat  = (const float*)d_in[1];
  const float* cs    = (const float*)d_in[2];
  const float* mask  = (const float*)d_in[3];
  const float* ck    = (const float*)d_in[4];
  const float* w     = (const float*)d_in[5];
  const float* mu    = (const float*)d_in[6];
  const float* sigma = (const float*)d_in[7];
  const float* lamb  = (const float*)d_in[8];
  float* out = (float*)d_out;

  // ws layout (u32 words):
  //  Fpk @0          102400  (fragment-packed, swizzled DFT matrix)
  //  Wpk @102400     5760
  //  Wt  @108160     5632
  //  Tab @113792     4160
  //  At  @117952     819200
  //  Ru  @937152     819200
  //  big @1756352    12288000
  //   conv phase: fukT [7485696 w]
  //   DC phase:   X0T @big [6144000] ; P2T @big+6144000 [6144000] ; Q @big
  unsigned int* wsw = (unsigned int*)d_ws;
  unsigned int* Fpk = wsw;
  unsigned int* Wpk = wsw + 102400;
  unsigned short* Wt = (unsigned short*)(wsw + 108160);
  unsigned short* Tab = (unsigned short*)(wsw + 113792);
  float* At = (float*)(wsw + 117952);
  float* Ru = (float*)(wsw + 937152);
  unsigned int* big = wsw + 1756352;
  unsigned short* fukT = (unsigned short*)big;
  unsigned int* X0T = big;
  unsigned int* P2T = big + 6144000;
  unsigned int* Q = big;

  k_dft<<<(HW + 255) / 256, 256, 0, stream>>>(Fpk);
  k_prep<<<(32 * 176 + 255) / 256, 256, 0, stream>>>(ck, Wpk);
  k_prep2<<<(2 * 11 * 16 * 32 + 255) / 256, 256, 0, stream>>>(ck, Wt);
  k_rbftab<<<32, 320, 0, stream>>>(w, mu, sigma, Tab);
  k_conv_rbf_mfma<<<dim3(22, 22, NN), 256, 0, stream>>>(u_t, Wpk, Tab, fukT);
  k_convT_mfma<<<dim3(10, 20, NN), 256, 0, stream>>>(fukT, Wt, Ru);
  k_umulT<<<dim3(100, 60), 256, 0, stream>>>(u_t, cs, X0T);
  k_dcpair<1><<<600, 256, 0, stream>>>(Fpk, X0T, mask, fdat, P2T);
  k_dcpair<2><<<600, 256, 0, stream>>>(Fpk, P2T, nullptr, nullptr, Q);
  k_coilsum<<<(NN * HW + 255) / 256, 256, 0, stream>>>(Q, cs, At);
  k_final<<<(NN * HW * 2 + 255) / 256, 256, 0, stream>>>(u_t, Ru, At, lamb, out);
}

// Round 7
// 350.103 us; speedup vs baseline: 1.3095x; 1.0864x over previous
//
#include <hip/hip_runtime.h>
#include <hip/hip_bf16.h>
#include <math.h>

#define NN 4
#define CC 15
#define HH 320
#define WW 320
#define HW (HH*WW)          // 102400
#define FF 32
#define KS 11
#define PADN 11
#define CPAD 5
#define HP 342
#define NK 31
#define NCB (NN*CC)
#define TABN 256            // intervals; 257 entries, stride 260

typedef short bf16x8 __attribute__((ext_vector_type(8)));
typedef float f32x4 __attribute__((ext_vector_type(4)));
typedef unsigned short u16x4 __attribute__((ext_vector_type(4)));

#define MFMA16 __builtin_amdgcn_mfma_f32_16x16x32_bf16

__device__ __forceinline__ unsigned int pack_bf(float r, float i) {
  __hip_bfloat16 hr = __float2bfloat16(r), hi = __float2bfloat16(i);
  unsigned short ur = *(unsigned short*)&hr, ui = *(unsigned short*)&hi;
  return (unsigned int)ur | ((unsigned int)ui << 16);
}
__device__ __forceinline__ unsigned short f2b(float x) {
  __hip_bfloat16 h = __float2bfloat16(x);
  return *(unsigned short*)&h;
}
__device__ __forceinline__ float b2f(unsigned short u) {
  __hip_bfloat16 h = *(__hip_bfloat16*)&u;
  return __bfloat162float(h);
}
__device__ __forceinline__ unsigned int rot16(unsigned int x) {
  return (x >> 16) | (x << 16);
}
// complex-pair fragment transforms
__device__ __forceinline__ bf16x8 xf4(uint4 p, unsigned int x) {
  union { unsigned int u[4]; bf16x8 v; } t;
  t.u[0] = p.x ^ x; t.u[1] = p.y ^ x; t.u[2] = p.z ^ x; t.u[3] = p.w ^ x;
  return t.v;
}
__device__ __forceinline__ bf16x8 xr4(uint4 p, unsigned int x) {
  union { unsigned int u[4]; bf16x8 v; } t;
  t.u[0] = rot16(p.x) ^ x; t.u[1] = rot16(p.y) ^ x;
  t.u[2] = rot16(p.z) ^ x; t.u[3] = rot16(p.w) ^ x;
  return t.v;
}
// chunk-granular (16B) XOR swizzle inside a 256-word fragment; involution.
__device__ __forceinline__ int swzw(int w) {
  int c = w >> 2;
  c ^= (c >> 3) & 7;
  return (c << 2) | (w & 3);
}
// fragment-packed index (swizzled): [row][col] -> frag(row>>4, col>>4), word
// swzw((row&15)*16 + (col&15)). All packed buffers use this layout.
__device__ __forceinline__ size_t pk_idx(int row, int col) {
  return (size_t)((row >> 4) * 20 + (col >> 4)) * 256 + swzw((row & 15) * 16 + (col & 15));
}

// ---------------- K0: centered orthonormal DFT matrix, bf16 pairs, PACKED --
__global__ void k_dft(unsigned int* __restrict__ Fpk) {
  int idx = blockIdx.x * blockDim.x + threadIdx.x;
  if (idx >= HW) return;
  int k = idx / WW, n = idx % WW;
  int prod = (k - 160) * (n - 160);
  int r = prod % 320; if (r < 0) r += 320;
  float ang = -6.283185307179586f * (float)r / 320.0f;
  const float s = 0.05590169943749474f; // 1/sqrt(320)
  Fpk[pk_idx(k, n)] = pack_bf(cosf(ang) * s, sinf(ang) * s);
}

// ---------------- K0b: prepack conv weights (forward, A-operand) -----------
__global__ void k_prep(const float* __restrict__ ck, unsigned int* __restrict__ Wpk) {
  int idx = blockIdx.x * blockDim.x + threadIdx.x;
  if (idx >= 32 * 176) return;
  int o = idx / 176, kw = idx % 176;
  int ky = kw / 16, kx = kw % 16;
  unsigned int v = 0;
  if (kx <= 10) {
    const float* p = &ck[(o * 121 + ky * 11 + kx) * 2];
    v = pack_bf(p[0], p[1]);
  }
  Wpk[idx] = v;
}

// ---------------- K0c: prepack adjoint weights Wt[ch][kx][ky16][o32] -------
__global__ void k_prep2(const float* __restrict__ ck, unsigned short* __restrict__ Wt) {
  int idx = blockIdx.x * blockDim.x + threadIdx.x;
  if (idx >= 2 * 11 * 16 * 32) return;
  int o = idx & 31;
  int ky = (idx >> 5) & 15;
  int rest = idx >> 9;
  int kx = rest % 11, ch = rest / 11;
  unsigned short v = 0;
  if (ky <= 10) v = f2b(ck[(o * 121 + ky * 11 + kx) * 2 + ch]);
  Wt[idx] = v;
}

// ---------------- K0d: RBF lookup table, bf16, [-2,2], 257 entries ---------
__global__ void k_rbftab(const float* __restrict__ w, const float* __restrict__ mu,
                         const float* __restrict__ sigma, unsigned short* __restrict__ Tab) {
  int o = blockIdx.x;
  int e = threadIdx.x;
  if (e >= TABN + 1) return;
  float v = -2.0f + (float)e * (4.0f / (float)TABN);
  float sg = sigma[0];
  float nInv = -1.0f / (2.0f * sg * sg);
  float acc = 0.f;
  for (int i = 0; i < NK; i++) {
    float d = v - mu[i];
    acc += w[o * NK + i] * __expf(d * d * nInv);
  }
  Tab[o * 260 + e] = f2b(acc);
}

// ---------------- K2: conv(11x11) + RBF(table) via MFMA implicit GEMM ------
__global__ __launch_bounds__(256) void k_conv_rbf_mfma(
    const float* __restrict__ u_t, const unsigned int* __restrict__ Wpk,
    const unsigned short* __restrict__ Tab, unsigned short* __restrict__ fukT) {
  __shared__ unsigned int lW[32 * 180];       // 23040 B
  __shared__ unsigned int tIn[26 * 32];       // 3328 B
  __shared__ unsigned short tab[32 * 260];    // 16640 B
  int n = blockIdx.z;
  int y0 = blockIdx.y * 16, x0 = blockIdx.x * 16;
  int tid = threadIdx.x;
  for (int i = tid; i < 32 * 176; i += 256)
    lW[(i / 176) * 180 + (i % 176)] = Wpk[i];
  {
    const unsigned int* Ts = (const unsigned int*)Tab;
    unsigned int* Td = (unsigned int*)tab;
    for (int i = tid; i < 32 * 130; i += 256) Td[i] = Ts[i];
  }
  for (int i = tid; i < 26 * 32; i += 256) {
    int rr = i >> 5, cc = i & 31;
    unsigned int v = 0;
    if (cc < 26) {
      int py = y0 + rr - 5, px = x0 + cc - 5;
      if (py >= 0 && py < HP && px >= 0 && px < HP) {
        int uy = py - PADN; uy = uy < 0 ? -uy : (uy >= HH ? 2 * (HH - 1) - uy : uy);
        int ux = px - PADN; ux = ux < 0 ? -ux : (ux >= WW ? 2 * (WW - 1) - ux : ux);
        const float* up = &u_t[((n * HH + uy) * WW + ux) * 2];
        v = pack_bf(up[0], up[1]);
      }
    }
    tIn[i] = v;
  }
  __syncthreads();
  int lane = tid & 63, wave = tid >> 6;
  int m16 = lane & 15, kq = lane >> 4;
  const short* lWs = (const short*)lW;
  f32x4 acc[4][2] = {};
  for (int ky = 0; ky < 11; ky++) {
    bf16x8 af0 = *(const bf16x8*)&lWs[m16 * 360 + ky * 32 + kq * 8];
    bf16x8 af1 = *(const bf16x8*)&lWs[(m16 + 16) * 360 + ky * 32 + kq * 8];
    #pragma unroll
    for (int nt = 0; nt < 4; nt++) {
      int rr = wave * 4 + nt + ky;
      int c0 = rr * 32 + m16 + kq * 4;
      union { unsigned int u[4]; bf16x8 v; } bu;
      bu.u[0] = tIn[c0]; bu.u[1] = tIn[c0 + 1];
      bu.u[2] = tIn[c0 + 2]; bu.u[3] = tIn[c0 + 3];
      acc[nt][0] = MFMA16(af0, bu.v, acc[nt][0], 0, 0, 0);
      acc[nt][1] = MFMA16(af1, bu.v, acc[nt][1], 0, 0, 0);
    }
  }
  const float tscale = (float)TABN / 4.0f;    // 64 per unit v
  #pragma unroll
  for (int nt = 0; nt < 4; nt++) {
    int Y = y0 + wave * 4 + nt;
    int X = x0 + m16;
    if (Y >= HP || X >= HP) continue;
    #pragma unroll
    for (int mt = 0; mt < 2; mt++) {
      u16x4 pk;
      #pragma unroll
      for (int r = 0; r < 4; r++) {
        float v = acc[nt][mt][r];
        int o = mt * 16 + kq * 4 + r;
        float t = (v + 2.0f) * tscale;
        t = fminf(fmaxf(t, 0.0f), 255.999f);
        int i0 = (int)t;
        float fr = t - (float)i0;
        float a = b2f(tab[o * 260 + i0]);
        float bv = b2f(tab[o * 260 + i0 + 1]);
        pk[r] = f2b(a + (bv - a) * fr);
      }
      *(u16x4*)&fukT[(((size_t)n * HP + Y) * HP + X) * 32 + mt * 16 + kq * 4] = pk;
    }
  }
}

// ---------------- K3: transposed conv via MFMA -----------------------------
__global__ __launch_bounds__(256) void k_convT_mfma(
    const unsigned short* __restrict__ fukT, const unsigned short* __restrict__ Wt,
    float* __restrict__ Ru) {
  __shared__ unsigned short rowBuf[42 * 32];
  __shared__ float accS[16 * 67];
  int n = blockIdx.z;
  int y0 = blockIdx.y * 16, x0 = blockIdx.x * 32;
  int tid = threadIdx.x;
  int lane = tid & 63, wave = tid >> 6;
  int ch = wave >> 1, xh = wave & 1;
  int m16 = lane & 15, kq = lane >> 4;
  bf16x8 afr[11];
  #pragma unroll
  for (int kx = 0; kx < 11; kx++)
    afr[kx] = *(const bf16x8*)&Wt[((ch * 11 + kx) * 16 + m16) * 32 + kq * 8];
  for (int i = tid; i < 16 * 67; i += 256) accS[i] = 0.f;
  int xl = xh * 16 + m16;
  for (int t = 0; t < 26; t++) {
    int r = y0 + 6 + t;
    __syncthreads();
    {
      const unsigned int* src = (const unsigned int*)&fukT[(((size_t)n * HP + r) * HP + x0 + 6) * 32];
      unsigned int* dst = (unsigned int*)rowBuf;
      for (int i = tid; i < 42 * 16; i += 256) dst[i] = src[i];
    }
    __syncthreads();
    f32x4 dacc = {};
    #pragma unroll
    for (int kx = 0; kx < 11; kx++) {
      bf16x8 bfrag = *(const bf16x8*)&rowBuf[(xl + 10 - kx) * 32 + kq * 8];
      dacc = MFMA16(afr[kx], bfrag, dacc, 0, 0, 0);
    }
    #pragma unroll
    for (int rg = 0; rg < 4; rg++) {
      int ky = kq * 4 + rg;
      int y = t + ky - 10;
      if (ky <= 10 && y >= 0 && y < 16)
        accS[y * 67 + xl * 2 + ch] += dacc[rg];
    }
  }
  __syncthreads();
  int chO = tid & 1, xO = (tid >> 1) & 31, yb = tid >> 6;
  #pragma unroll
  for (int q = 0; q < 4; q++) {
    int y = yb + q * 4;
    Ru[(((size_t)n * HH + y0 + y) * WW + x0 + xO) * 2 + chO] = accS[y * 67 + xO * 2 + chO];
  }
}

// ---------------- K4: X0T = (u * coil_sens)^T, PACKED (swizzled) fragments -
__global__ __launch_bounds__(256) void k_umulT(const float* __restrict__ u_t,
                                               const float* __restrict__ cs,
                                               unsigned int* __restrict__ X0T) {
  __shared__ unsigned int t[32 * 33];
  int bc = blockIdx.x;                 // 0..99 tile
  int b = blockIdx.y;                  // 0..59 (n*CC+c)
  int n = b / CC;
  int ty = (bc / 10) * 32, tx = (bc % 10) * 32;
  int r = threadIdx.x >> 5, c = threadIdx.x & 31;
  #pragma unroll
  for (int q = 0; q < 4; q++) {
    int y = ty + r + q * 8, x = tx + c;
    const float* up = &u_t[((size_t)n * HW + (size_t)y * WW + x) * 2];
    const float* cp = &cs[((size_t)b * HW + (size_t)y * WW + x) * 2];
    float ur = up[0], ui = up[1], crr = cp[0], cii = cp[1];
    t[(r + q * 8) * 33 + c] = pack_bf(ur * crr - ui * cii, ur * cii + ui * crr);
  }
  __syncthreads();
  #pragma unroll
  for (int q = 0; q < 4; q++) {
    int xx = r + q * 8;                // local x (transposed row)
    int x = tx + xx, y = ty + c;
    X0T[(size_t)b * HW + pk_idx(x, y)] = t[c * 33 + xx];
  }
}

// ---------------- K5: fused double complex GEMM via async LDS-DMA ----------
// 32-row strips, 4 waves (4 col-groups of 80), 600 blocks, wave tile (2,5).
// LDS = 80 KB exactly: sA 40 KB (A-strip / T-park) + 2-deep 20 KB DMA ring
// -> 2 blocks/CU (round 5's 120 KB gave 1 block/CU, 1 wave/SIMD, all latency
// exposed). K-loop keeps round-5's PROVEN order: DMA issue -> counted vmcnt
// -> sched_barrier(0) (rule #18: pin schedule after inline-asm waitcnt) ->
// ALL LDS reads -> MFMAs. Depth-2 counts: vmcnt(5) retires row kf before its
// ds_read; the prior buffer's reads retired (lgkmcnt before MFMA use) before
// the overwriting DMA is issued, so no WAR.
// MODE 1: P2 = mask .* (F*X0*F - f)  (TRANSPOSED-PACKED out, direct stores)
// MODE 2: Q = conj(F)*P2*conj(F) = conj(conj(T)*F)  (natural out)
template <int MODE>
__global__ __launch_bounds__(256, 2) void k_dcpair(
    const unsigned int* __restrict__ Fpk,   // packed F fragments (swizzled)
    const unsigned int* __restrict__ Bp,    // packed B fragments per batch
    const float* __restrict__ mask, const float* __restrict__ fdat,
    unsigned int* __restrict__ Out) {
  __shared__ unsigned int sA[10240];        // 40 KB: A-strip / T-park
  __shared__ unsigned int sB[2][5120];      // 40 KB: 2-deep DMA ring
  int bid = blockIdx.x;
  int wg = (bid & 7) * 75 + (bid >> 3);     // XCD swizzle (600 = 8*75, bijective)
  int b = wg / 10, strip = wg % 10;
  int i0 = strip * 32;
  int tid = threadIdx.x;
  int lane = tid & 63, wc = tid >> 6;       // 4 waves = 4 col groups of 80
  int m16 = lane & 15, kq = lane >> 4;
  int loff = m16 * 16 + kq * 4;             // logical lane word offset in frag
  int loffS = swzw(loff);                   // physical (swizzled) offset
  const unsigned int XA1 = (MODE == 1) ? 0x80000000u : 0u;
  const unsigned int XA2 = (MODE == 1) ? 0u : 0x00008000u;

  const unsigned int* Astrip = Fpk + (size_t)strip * 10240;
  const unsigned int* Bb = Bp + (size_t)b * HW + (size_t)(wc * 5) * 5120;
  const unsigned int* Fb = Fpk + (size_t)(wc * 5) * 5120;

  // ---- prologue: DMA A strip (10 frags/wave) + B row 0 ----
  #pragma unroll
  for (int f = 0; f < 10; f++)
    __builtin_amdgcn_global_load_lds(Astrip + (wc * 10 + f) * 256 + lane * 4,
                                     &sA[(wc * 10 + f) * 256], 16, 0, 0);
  #pragma unroll
  for (int ct = 0; ct < 5; ct++)
    __builtin_amdgcn_global_load_lds(Bb + ct * 5120 + lane * 4,
                                     &sB[0][(wc * 5 + ct) * 256], 16, 0, 0);
  __syncthreads();   // drains vmcnt(0): A + row 0 landed; A visible to all

  // ---- stage 1: T = (A-transform F) * B, barrier-free ----
  f32x4 aR0[5] = {}, aI0[5] = {}, aR1[5] = {}, aI1[5] = {};
  #pragma unroll
  for (int kf = 0; kf < 20; kf++) {
    if (kf < 19) {
      unsigned int* stb = sB[(kf + 1) & 1];
      #pragma unroll
      for (int ct = 0; ct < 5; ct++)
        __builtin_amdgcn_global_load_lds(Bb + ct * 5120 + (kf + 1) * 256 + lane * 4,
                                         &stb[(wc * 5 + ct) * 256], 16, 0, 0);
      asm volatile("s_waitcnt vmcnt(5)" ::: "memory");
    } else {
      asm volatile("s_waitcnt vmcnt(0)" ::: "memory");
    }
    __builtin_amdgcn_sched_barrier(0);
    const unsigned int* rdb = sB[kf & 1];
    uint4 a0 = *(const uint4*)&sA[kf * 256 + loffS];
    uint4 a1 = *(const uint4*)&sA[5120 + kf * 256 + loffS];
    bf16x8 x10 = xf4(a0, XA1), x20 = xr4(a0, XA2);
    bf16x8 x11 = xf4(a1, XA1), x21 = xr4(a1, XA2);
    #pragma unroll
    for (int ct = 0; ct < 5; ct++) {
      uint4 bq = *(const uint4*)&rdb[(wc * 5 + ct) * 256 + loffS];
      bf16x8 bb = *(const bf16x8*)&bq;
      aR0[ct] = MFMA16(x10, bb, aR0[ct], 0, 0, 0);
      aI0[ct] = MFMA16(x20, bb, aI0[ct], 0, 0, 0);
      aR1[ct] = MFMA16(x11, bb, aR1[ct], 0, 0, 0);
      aI1[ct] = MFMA16(x21, bb, aI1[ct], 0, 0, 0);
    }
  }

  // ---- park T in sA (conj for MODE 2); DMA F row 0 ----
  __syncthreads();   // all waves done reading A-strip
  #pragma unroll
  for (int ct = 0; ct < 5; ct++)
    #pragma unroll
    for (int r = 0; r < 4; r++) {
      unsigned int v0 = pack_bf(aR0[ct][r], aI0[ct][r]);
      unsigned int v1 = pack_bf(aR1[ct][r], aI1[ct][r]);
      if (MODE == 2) { v0 ^= 0x80000000u; v1 ^= 0x80000000u; }
      int w = swzw((kq * 4 + r) * 16 + m16);
      sA[(wc * 5 + ct) * 256 + w] = v0;
      sA[(20 + wc * 5 + ct) * 256 + w] = v1;
    }
  #pragma unroll
  for (int ct = 0; ct < 5; ct++)
    __builtin_amdgcn_global_load_lds(Fb + ct * 5120 + lane * 4,
                                     &sB[0][(wc * 5 + ct) * 256], 16, 0, 0);
  __syncthreads();   // T visible; F row 0 drained

  // ---- stage 2: Out = T * F, barrier-free (B = raw F for both modes) ----
  f32x4 cR0[5] = {}, cI0[5] = {}, cR1[5] = {}, cI1[5] = {};
  #pragma unroll
  for (int kf = 0; kf < 20; kf++) {
    if (kf < 19) {
      unsigned int* stb = sB[(kf + 1) & 1];
      #pragma unroll
      for (int ct = 0; ct < 5; ct++)
        __builtin_amdgcn_global_load_lds(Fb + ct * 5120 + (kf + 1) * 256 + lane * 4,
                                         &stb[(wc * 5 + ct) * 256], 16, 0, 0);
      asm volatile("s_waitcnt vmcnt(5)" ::: "memory");
    } else {
      asm volatile("s_waitcnt vmcnt(0)" ::: "memory");
    }
    __builtin_amdgcn_sched_barrier(0);
    const unsigned int* rdb = sB[kf & 1];
    uint4 t0 = *(const uint4*)&sA[kf * 256 + loffS];
    uint4 t1 = *(const uint4*)&sA[5120 + kf * 256 + loffS];
    bf16x8 x10 = xf4(t0, 0x80000000u), x20 = xr4(t0, 0u);
    bf16x8 x11 = xf4(t1, 0x80000000u), x21 = xr4(t1, 0u);
    #pragma unroll
    for (int ct = 0; ct < 5; ct++) {
      uint4 bq = *(const uint4*)&rdb[(wc * 5 + ct) * 256 + loffS];
      bf16x8 bb = *(const bf16x8*)&bq;
      cR0[ct] = MFMA16(x10, bb, cR0[ct], 0, 0, 0);
      cI0[ct] = MFMA16(x20, bb, cI0[ct], 0, 0, 0);
      cR1[ct] = MFMA16(x11, bb, cR1[ct], 0, 0, 0);
      cI1[ct] = MFMA16(x21, bb, cI1[ct], 0, 0, 0);
    }
  }

  // ---- epilogue ----
  if constexpr (MODE == 1) {
    // Direct packed-transposed frag stores: C layout (col=m16, row=kq*4+r)
    // makes each (ct, rowfrag) a single contiguous uint4 at word loff.
    int n = b / CC;
    #pragma unroll
    for (int ct = 0; ct < 5; ct++) {
      int col = wc * 80 + ct * 16 + m16;
      uint4 s0, s1;
      #pragma unroll
      for (int r = 0; r < 4; r++) {
        int row0 = i0 + kq * 4 + r;
        float m0 = mask[n * HW + row0 * WW + col];
        size_t f0i = ((size_t)b * HW + (size_t)row0 * WW + col) * 2;
        ((unsigned int*)&s0)[r] =
            pack_bf(m0 * (cR0[ct][r] - fdat[f0i]), m0 * (cI0[ct][r] - fdat[f0i + 1]));
        int row1 = row0 + 16;
        float m1 = mask[n * HW + row1 * WW + col];
        size_t f1i = ((size_t)b * HW + (size_t)row1 * WW + col) * 2;
        ((unsigned int*)&s1)[r] =
            pack_bf(m1 * (cR1[ct][r] - fdat[f1i]), m1 * (cI1[ct][r] - fdat[f1i + 1]));
      }
      size_t base = (size_t)b * HW + (size_t)((wc * 5 + ct) * 20 + strip * 2) * 256 + loffS;
      *(uint4*)&Out[base] = s0;
      *(uint4*)&Out[base + 256] = s1;
    }
  } else {
    // natural layout for k_coilsum; conjugate on store
    #pragma unroll
    for (int ct = 0; ct < 5; ct++)
      #pragma unroll
      for (int r = 0; r < 4; r++) {
        int col = wc * 80 + ct * 16 + m16;
        int row0 = i0 + kq * 4 + r;
        int row1 = i0 + 16 + kq * 4 + r;
        Out[(size_t)b * HW + (size_t)row0 * WW + col] =
            pack_bf(cR0[ct][r], cI0[ct][r]) ^ 0x80000000u;
        Out[(size_t)b * HW + (size_t)row1 * WW + col] =
            pack_bf(cR1[ct][r], cI1[ct][r]) ^ 0x80000000u;
      }
  }
}

// ---------------- K6: coil-combine with conj(sens), bf16-pair input --------
__global__ void k_coilsum(const unsigned int* __restrict__ Z, const float* __restrict__ cs,
                          float* __restrict__ At) {
  int idx = blockIdx.x * blockDim.x + threadIdx.x;
  if (idx >= NN * HW) return;
  int n = idx / HW, hw = idx % HW;
  float ar = 0.f, ai = 0.f;
  for (int c = 0; c < CC; c++) {
    size_t zi = (size_t)(n * CC + c) * HW + hw;
    unsigned int p = Z[zi];
    float zr = b2f((unsigned short)(p & 0xffff));
    float zim = b2f((unsigned short)(p >> 16));
    float crr = cs[zi * 2], cii = cs[zi * 2 + 1];
    ar += zr * crr + zim * cii;
    ai += zim * crr - zr * cii;
  }
  At[idx * 2] = ar;
  At[idx * 2 + 1] = ai;
}

// ---------------- K7: out = u - Ru/FF - lamb*At ----------------------------
__global__ void k_final(const float* __restrict__ u_t, const float* __restrict__ Ru,
                        const float* __restrict__ At, const float* __restrict__ lamb,
                        float* __restrict__ out) {
  int idx = blockIdx.x * blockDim.x + threadIdx.x;
  if (idx >= NN * HW * 2) return;
  out[idx] = u_t[idx] - Ru[idx] * (1.0f / (float)FF) - lamb[0] * At[idx];
}

extern "C" void kernel_launch(void* const* d_in, const int* in_sizes, int n_in,
                              void* d_out, int out_size, void* d_ws, size_t ws_size,
                              hipStream_t stream) {
  const float* u_t   = (const float*)d_in[0];
  const float* fdat  = (const float*)d_in[1];
  const float* cs    = (const float*)d_in[2];
  const float* mask  = (const float*)d_in[3];
  const float* ck    = (const float*)d_in[4];
  const float* w     = (const float*)d_in[5];
  const float* mu    = (const float*)d_in[6];
  const float* sigma = (const float*)d_in[7];
  const float* lamb  = (const float*)d_in[8];
  float* out = (float*)d_out;

  // ws layout (u32 words):
  //  Fpk @0          102400  (fragment-packed, swizzled DFT matrix)
  //  Wpk @102400     5760
  //  Wt  @108160     5632
  //  Tab @113792     4160
  //  At  @117952     819200
  //  Ru  @937152     819200
  //  big @1756352    12288000
  //   conv phase: fukT [7485696 w]
  //   DC phase:   X0T @big [6144000] ; P2T @big+6144000 [6144000] ; Q @big
  unsigned int* wsw = (unsigned int*)d_ws;
  unsigned int* Fpk = wsw;
  unsigned int* Wpk = wsw + 102400;
  unsigned short* Wt = (unsigned short*)(wsw + 108160);
  unsigned short* Tab = (unsigned short*)(wsw + 113792);
  float* At = (float*)(wsw + 117952);
  float* Ru = (float*)(wsw + 937152);
  unsigned int* big = wsw + 1756352;
  unsigned short* fukT = (unsigned short*)big;
  unsigned int* X0T = big;
  unsigned int* P2T = big + 6144000;
  unsigned int* Q = big;

  k_dft<<<(HW + 255) / 256, 256, 0, stream>>>(Fpk);
  k_prep<<<(32 * 176 + 255) / 256, 256, 0, stream>>>(ck, Wpk);
  k_prep2<<<(2 * 11 * 16 * 32 + 255) / 256, 256, 0, stream>>>(ck, Wt);
  k_rbftab<<<32, 320, 0, stream>>>(w, mu, sigma, Tab);
  k_conv_rbf_mfma<<<dim3(22, 22, NN), 256, 0, stream>>>(u_t, Wpk, Tab, fukT);
  k_convT_mfma<<<dim3(10, 20, NN), 256, 0, stream>>>(fukT, Wt, Ru);
  k_umulT<<<dim3(100, 60), 256, 0, stream>>>(u_t, cs, X0T);
  k_dcpair<1><<<600, 256, 0, stream>>>(Fpk, X0T, mask, fdat, P2T);
  k_dcpair<2><<<600, 256, 0, stream>>>(Fpk, P2T, nullptr, nullptr, Q);
  k_coilsum<<<(NN * HW + 255) / 256, 256, 0, stream>>>(Q, cs, At);
  k_final<<<(NN * HW * 2 + 255) / 256, 256, 0, stream>>>(u_t, Ru, At, lamb, out);
}